// Round 2
// 2488.340 us; speedup vs baseline: 4.1847x; 4.1847x over previous
//
#include <hip/hip_runtime.h>
#include <hip/hip_bf16.h>
#include <math.h>

typedef __bf16  bf16x8 __attribute__((ext_vector_type(8)));
typedef __bf16  bf16x4 __attribute__((ext_vector_type(4)));
typedef __bf16  bf16x2 __attribute__((ext_vector_type(2)));
typedef float   f32x4  __attribute__((ext_vector_type(4)));
typedef unsigned int uint32;

#define HIDDEN 4096
#define NHQ    32
#define NHKV   8
#define HD     128
#define SEQ    2048
#define BATCH  2
#define NTOK   (BATCH * SEQ)
#define KVDIM  (NHKV * HD)   // 1024

// ---------------------------------------------------------------------------
// Load 8 contiguous elements as bf16, converting from fp32 if needed.
// ---------------------------------------------------------------------------
__device__ inline void load8(const float* p, __bf16* d)
{
    float4 a = *reinterpret_cast<const float4*>(p);
    float4 b = *reinterpret_cast<const float4*>(p + 4);
    d[0] = (__bf16)a.x; d[1] = (__bf16)a.y; d[2] = (__bf16)a.z; d[3] = (__bf16)a.w;
    d[4] = (__bf16)b.x; d[5] = (__bf16)b.y; d[6] = (__bf16)b.z; d[7] = (__bf16)b.w;
}
__device__ inline void load8(const __hip_bfloat16* p, __bf16* d)
{
    *reinterpret_cast<bf16x8*>(d) = *reinterpret_cast<const bf16x8*>(p);
}

__device__ inline void storeC(float* C, size_t idx, float v)          { C[idx] = v; }
__device__ inline void storeC(__hip_bfloat16* C, size_t idx, float v) { C[idx] = __float2bfloat16(v); }

// ---------------------------------------------------------------------------
// GEMM: C = A @ B, A[M][K] (TA), B[K][N] (TB), C (TC: float or bf16).
// Block: 256 thr = 4 waves (2x2), tile BM=64 BN=64 BK=32.
// (unchanged from verified version)
// ---------------------------------------------------------------------------
#define BM 64
#define BN 64
#define BK 32
#define LDSS 40   // padded leading dim (elems); 40*2B=80B => 16B-aligned rows

template <typename TA, typename TB, typename TC>
__global__ __launch_bounds__(256) void gemm_to(
    const TA* __restrict__ A,
    const TB* __restrict__ B,
    TC* __restrict__ C,
    int M, int N, int K)
{
    __shared__ __align__(16) __bf16 As[BM][LDSS];       // As[m][k]
    __shared__ __align__(16) __bf16 Bs[BN][LDSS];       // transposed: Bs[n][k]

    const int tid  = threadIdx.x;
    const int bm   = blockIdx.y * BM;
    const int bn   = blockIdx.x * BN;
    const int wave = tid >> 6;
    const int lane = tid & 63;
    const int wr   = (wave >> 1) * 32;    // wave row offset in tile
    const int wc   = (wave & 1) * 32;     // wave col offset in tile
    const int lrow = lane & 15;
    const int lq   = lane >> 4;           // 0..3

    f32x4 acc[2][2] = {};

    const int ar = tid >> 2;              // 0..63   (A tile row)
    const int ac = (tid & 3) * 8;         // 0..24   (A tile k)
    const int br = tid >> 3;              // 0..31   (B tile k)
    const int bc = (tid & 7) * 8;         // 0..56   (B tile n)

    for (int k0 = 0; k0 < K; k0 += BK) {
        __bf16 abuf[8], bbuf[8];
        load8(A + (size_t)(bm + ar) * K + (k0 + ac), abuf);
        load8(B + (size_t)(k0 + br) * N + (bn + bc), bbuf);

        *reinterpret_cast<bf16x8*>(&As[ar][ac]) = *reinterpret_cast<bf16x8*>(abuf);
        #pragma unroll
        for (int j = 0; j < 8; ++j)
            Bs[bc + j][br] = bbuf[j];

        __syncthreads();

        bf16x8 afrag[2], bfrag[2];
        #pragma unroll
        for (int mi = 0; mi < 2; ++mi)
            afrag[mi] = *reinterpret_cast<const bf16x8*>(&As[wr + mi * 16 + lrow][lq * 8]);
        #pragma unroll
        for (int ni = 0; ni < 2; ++ni)
            bfrag[ni] = *reinterpret_cast<const bf16x8*>(&Bs[wc + ni * 16 + lrow][lq * 8]);

        #pragma unroll
        for (int mi = 0; mi < 2; ++mi)
            #pragma unroll
            for (int ni = 0; ni < 2; ++ni)
                acc[mi][ni] = __builtin_amdgcn_mfma_f32_16x16x32_bf16(
                    afrag[mi], bfrag[ni], acc[mi][ni], 0, 0, 0);

        __syncthreads();
    }

    // Epilogue: D layout col=lane&15, row=(lane>>4)*4+reg
    #pragma unroll
    for (int mi = 0; mi < 2; ++mi)
        #pragma unroll
        for (int ni = 0; ni < 2; ++ni)
            #pragma unroll
            for (int r = 0; r < 4; ++r) {
                int row = bm + wr + mi * 16 + lq * 4 + r;
                int col = bn + wc + ni * 16 + lrow;
                storeC(C, (size_t)row * N + col, acc[mi][ni][r]);
            }
}

// ---------------------------------------------------------------------------
// RoPE in-place on bf16. X layout: [tok][h*HD + d], pairs (i, i+64), i in 0..63.
// (unchanged)
// ---------------------------------------------------------------------------
__global__ __launch_bounds__(256) void rope_kernel(
    __hip_bfloat16* __restrict__ X, int nh, size_t total)
{
    size_t idx = (size_t)blockIdx.x * blockDim.x + threadIdx.x;
    if (idx >= total) return;
    int    i   = (int)(idx & 63);
    size_t t   = idx >> 6;
    int    h   = (int)(t % nh);
    size_t tok = t / nh;
    int    pos = (int)(tok & (SEQ - 1));

    float inv_freq = exp2f(-(float)i * (13.287712379549449f / 64.0f));
    float fr = (float)pos * inv_freq;
    float sv, cv;
    sincosf(fr, &sv, &cv);

    size_t base = tok * ((size_t)nh * HD) + (size_t)h * HD + i;
    float x1 = __bfloat162float(X[base]);
    float x2 = __bfloat162float(X[base + 64]);
    X[base]      = __float2bfloat16(x1 * cv - x2 * sv);
    X[base + 64] = __float2bfloat16(x2 * cv + x1 * sv);
}

// ---------------------------------------------------------------------------
// V transpose: Vb [b*SEQ + s][KVDIM] -> Vt [b*KVDIM + dg][SEQ]
// 32x32 LDS tiles, 8B vector global accesses both sides.
// ---------------------------------------------------------------------------
__global__ __launch_bounds__(256) void transpose_v(
    const __hip_bfloat16* __restrict__ Vb,
    __hip_bfloat16* __restrict__ Vt)
{
    __shared__ __align__(16) __bf16 t[32][36];   // pad 36: 72B rows keep 8B align
    const int bz = blockIdx.z;
    const int s0 = blockIdx.x * 32;
    const int c0 = blockIdx.y * 32;
    const int r  = threadIdx.x >> 3;         // 0..31
    const int c4 = (threadIdx.x & 7) * 4;    // 0,4,...,28

    *reinterpret_cast<bf16x4*>(&t[r][c4]) =
        *reinterpret_cast<const bf16x4*>(Vb + ((size_t)bz * SEQ + s0 + r) * KVDIM + c0 + c4);
    __syncthreads();

    bf16x4 o;
    o[0] = t[c4 + 0][r]; o[1] = t[c4 + 1][r];
    o[2] = t[c4 + 2][r]; o[3] = t[c4 + 3][r];
    *reinterpret_cast<bf16x4*>(Vt + ((size_t)bz * KVDIM + c0 + r) * SEQ + s0 + c4) = o;
}

// ---------------------------------------------------------------------------
// Flash attention with MFMA. One wave = 16 query rows of one q-head.
// Block = 4 waves = the 4 q-heads sharing one KV head (same K/V tiles -> L2 hot).
// No __syncthreads: waves fully independent; LDS statically partitioned per wave.
//
// Per 32-key KV tile:
//   S^T[k][q] = K·Q^T  via 8 mfma_16x16x32 (A=K rows contiguous, B=Q rows contiguous)
//   online softmax on S^T (in-lane 8 vals + shfl_xor 16/32 per q-column)
//   P -> bf16 via per-wave LDS turnaround (Pl[q][k], pad 40)
//   O^T[d][q] += V^T·P^T via 8 mfma (A = rows of pre-transposed Vt, contiguous)
// Epilogue: O^T -> LDS [q][d] -> coalesced bf16x8 global store.
// O aliases Q safely: wave reads only its own 16 q-rows (once, at start).
// ---------------------------------------------------------------------------
__global__ __launch_bounds__(256) void attn_mfma(
    const __hip_bfloat16* __restrict__ Qg,   // [NTOK][HIDDEN]
    const __hip_bfloat16* __restrict__ Kg,   // [NTOK][KVDIM]
    const __hip_bfloat16* __restrict__ Vt,   // [B*KVDIM][SEQ]
    __hip_bfloat16* __restrict__ Og)         // [NTOK][HIDDEN] (may alias Qg)
{
    __shared__ __align__(16) __bf16 Pl[4][16][40];
    __shared__ __align__(16) __bf16 Ol[4][16][136];

    const int wv   = threadIdx.x >> 6;
    const int lane = threadIdx.x & 63;
    const int lq   = lane & 15;   // q column index (D-layout col)
    const int g    = lane >> 4;   // lane group  (D-layout row = 4g+r)

    const int bid = blockIdx.x;              // [0, 2048)
    const int qt  = 127 - (bid & 127);       // heavy q-tiles dispatched first
    const int khb = bid >> 7;                // [0, 16)
    const int b   = khb >> 3;
    const int kh  = khb & 7;
    const int qh  = kh * 4 + wv;
    const int q0  = qt * 16;
    const int q_g = q0 + lq;

    // Q fragments (MFMA B-operand layout): lane reads its q-row, d = dj*32 + g*8
    const __hip_bfloat16* qrow = Qg + ((size_t)b * SEQ + q0 + lq) * HIDDEN + (size_t)qh * HD;
    bf16x8 qf[4];
#pragma unroll
    for (int dj = 0; dj < 4; ++dj)
        qf[dj] = *reinterpret_cast<const bf16x8*>(qrow + dj * 32 + g * 8);

    const __hip_bfloat16* Kb = Kg + ((size_t)b * SEQ) * KVDIM + (size_t)kh * HD;
    const __hip_bfloat16* Vb = Vt + ((size_t)b * KVDIM + (size_t)kh * HD) * SEQ;

    f32x4 oacc[8] = {};                      // O^T[d = dt*16 + 4g + r][q = lq]
    float m_run = -INFINITY, l_run = 0.0f;
    const float SCALE = 0.08838834764831845f;   // 1/sqrt(128)

    const int kv_len = q0 + 16;
    for (int k0 = 0; k0 < kv_len; k0 += 32) {
        // ---- S^T = K · Q^T : sacc[kt] covers keys k0+kt*16 .. +16
        f32x4 sacc[2] = {};
#pragma unroll
        for (int kt = 0; kt < 2; ++kt) {
            const __hip_bfloat16* krow = Kb + (size_t)(k0 + kt * 16 + lq) * KVDIM;
#pragma unroll
            for (int dj = 0; dj < 4; ++dj) {
                bf16x8 kf = *reinterpret_cast<const bf16x8*>(krow + dj * 32 + g * 8);
                sacc[kt] = __builtin_amdgcn_mfma_f32_16x16x32_bf16(kf, qf[dj], sacc[kt], 0, 0, 0);
            }
        }

        // ---- scale + causal mask + tile max (per q-column)
        float p[2][4];
        float tmax = -INFINITY;
#pragma unroll
        for (int kt = 0; kt < 2; ++kt)
#pragma unroll
            for (int r = 0; r < 4; ++r) {
                int   k_g = k0 + kt * 16 + 4 * g + r;
                float s   = sacc[kt][r] * SCALE;
                s = (k_g <= q_g) ? s : -INFINITY;
                p[kt][r] = s;
                tmax = fmaxf(tmax, s);
            }
        tmax = fmaxf(tmax, __shfl_xor(tmax, 16));
        tmax = fmaxf(tmax, __shfl_xor(tmax, 32));

        float m_new = fmaxf(m_run, tmax);
        float corr  = __expf(m_run - m_new);     // 0 on first tile (m_run = -inf)
        float tsum  = 0.0f;
#pragma unroll
        for (int kt = 0; kt < 2; ++kt)
#pragma unroll
            for (int r = 0; r < 4; ++r) {
                float e = __expf(p[kt][r] - m_new);   // masked -> exp(-inf) = 0
                p[kt][r] = e;
                tsum += e;
            }
        tsum += __shfl_xor(tsum, 16);
        tsum += __shfl_xor(tsum, 32);
        l_run = l_run * corr + tsum;
        m_run = m_new;

        // ---- P -> bf16 via per-wave LDS turnaround: Pl[q][k-within-tile]
#pragma unroll
        for (int kt = 0; kt < 2; ++kt) {
            bf16x2 lo, hi;
            lo[0] = (__bf16)p[kt][0]; lo[1] = (__bf16)p[kt][1];
            hi[0] = (__bf16)p[kt][2]; hi[1] = (__bf16)p[kt][3];
            *reinterpret_cast<bf16x2*>(&Pl[wv][lq][kt * 16 + 4 * g])     = lo;
            *reinterpret_cast<bf16x2*>(&Pl[wv][lq][kt * 16 + 4 * g + 2]) = hi;
        }
        // B-operand read: lane needs P[q=lq][k = 8g .. 8g+8) (same-wave; LDS ops
        // from one wave complete in order; compiler may-alias keeps program order)
        bf16x8 pf = *reinterpret_cast<const bf16x8*>(&Pl[wv][lq][8 * g]);

        // ---- rescale accumulator, then O^T += V^T · P^T
#pragma unroll
        for (int dt = 0; dt < 8; ++dt) {
            oacc[dt][0] *= corr; oacc[dt][1] *= corr;
            oacc[dt][2] *= corr; oacc[dt][3] *= corr;
        }
#pragma unroll
        for (int dt = 0; dt < 8; ++dt) {
            bf16x8 vf = *reinterpret_cast<const bf16x8*>(
                Vb + (size_t)(dt * 16 + lq) * SEQ + k0 + 8 * g);
            oacc[dt] = __builtin_amdgcn_mfma_f32_16x16x32_bf16(vf, pf, oacc[dt], 0, 0, 0);
        }
    }

    // ---- epilogue: normalize, transpose O^T -> Ol[q][d] in LDS, coalesced store
    float inv = 1.0f / l_run;
#pragma unroll
    for (int dt = 0; dt < 8; ++dt) {
        bf16x2 lo, hi;
        lo[0] = (__bf16)(oacc[dt][0] * inv); lo[1] = (__bf16)(oacc[dt][1] * inv);
        hi[0] = (__bf16)(oacc[dt][2] * inv); hi[1] = (__bf16)(oacc[dt][3] * inv);
        *reinterpret_cast<bf16x2*>(&Ol[wv][lq][dt * 16 + 4 * g])     = lo;
        *reinterpret_cast<bf16x2*>(&Ol[wv][lq][dt * 16 + 4 * g + 2]) = hi;
    }

    // lane lq = q-row, chunks c = j*4 + g of 8 bf16: 64B contiguous per row per store
    __hip_bfloat16* orow = Og + ((size_t)b * SEQ + q0 + lq) * HIDDEN + (size_t)qh * HD;
#pragma unroll
    for (int j = 0; j < 4; ++j) {
        int c = j * 4 + g;
        bf16x8 v = *reinterpret_cast<const bf16x8*>(&Ol[wv][lq][c * 8]);
        *reinterpret_cast<bf16x8*>(orow + c * 8) = v;
    }
}

// ---------------------------------------------------------------------------
extern "C" void kernel_launch(void* const* d_in, const int* in_sizes, int n_in,
                              void* d_out, int out_size, void* d_ws, size_t ws_size,
                              hipStream_t stream)
{
    const float* x  = (const float*)d_in[0];
    const float* Wq = (const float*)d_in[1];
    const float* Wk = (const float*)d_in[2];
    const float* Wv = (const float*)d_in[3];
    const float* Wo = (const float*)d_in[4];
    float* out = (float*)d_out;

    char* ws = (char*)d_ws;
    __hip_bfloat16* Qb = (__hip_bfloat16*)ws;                                   // NTOK*HIDDEN bf16
    __hip_bfloat16* Kb = (__hip_bfloat16*)(ws + (size_t)NTOK * HIDDEN * 2);     // NTOK*KVDIM
    __hip_bfloat16* Vb = (__hip_bfloat16*)(ws + (size_t)NTOK * HIDDEN * 2
                                              + (size_t)NTOK * KVDIM * 2);      // NTOK*KVDIM

    // V^T scratch: prefer workspace (if sized), else tail of d_out (fully
    // consumed by attn_mfma before the final GEMM overwrites d_out).
    const size_t base_ws = (size_t)NTOK * HIDDEN * 2 + 2 * (size_t)NTOK * KVDIM * 2;
    const size_t vt_bytes = (size_t)NTOK * KVDIM * 2;
    __hip_bfloat16* Vtr = (ws_size >= base_ws + vt_bytes)
                        ? (__hip_bfloat16*)(ws + base_ws)
                        : (__hip_bfloat16*)d_out;

    dim3 blk(256);

    // Projections (fp32 inputs cast to bf16 while staging into LDS)
    gemm_to<float, float, __hip_bfloat16><<<dim3(HIDDEN / BN, NTOK / BM), blk, 0, stream>>>(
        x, Wq, Qb, NTOK, HIDDEN, HIDDEN);
    gemm_to<float, float, __hip_bfloat16><<<dim3(KVDIM / BN, NTOK / BM), blk, 0, stream>>>(
        x, Wk, Kb, NTOK, KVDIM, HIDDEN);
    gemm_to<float, float, __hip_bfloat16><<<dim3(KVDIM / BN, NTOK / BM), blk, 0, stream>>>(
        x, Wv, Vb, NTOK, KVDIM, HIDDEN);

    // RoPE (in place) on Q and K
    {
        size_t totq = (size_t)NTOK * NHQ * 64;
        size_t totk = (size_t)NTOK * NHKV * 64;
        rope_kernel<<<(unsigned)((totq + 255) / 256), blk, 0, stream>>>(Qb, NHQ,  totq);
        rope_kernel<<<(unsigned)((totk + 255) / 256), blk, 0, stream>>>(Kb, NHKV, totk);
    }

    // V transpose into scratch
    transpose_v<<<dim3(SEQ / 32, KVDIM / 32, BATCH), blk, 0, stream>>>(Vb, Vtr);

    // MFMA flash attention: O aliases Q buffer (per-wave read-before-write of own rows)
    attn_mfma<<<BATCH * NHKV * (SEQ / 16), blk, 0, stream>>>(Qb, Kb, Vtr, Qb);

    // Output projection: A = bf16 attention out, B = fp32 Wo, C = fp32 out
    gemm_to<__hip_bfloat16, float, float><<<dim3(HIDDEN / BN, NTOK / BM), blk, 0, stream>>>(
        Qb, Wo, out, NTOK, HIDDEN, HIDDEN);
}

// Round 5
// 1537.319 us; speedup vs baseline: 6.7734x; 1.6186x over previous
//
#include <hip/hip_runtime.h>
#include <hip/hip_bf16.h>
#include <math.h>

typedef __bf16  bf16x8 __attribute__((ext_vector_type(8)));
typedef __bf16  bf16x4 __attribute__((ext_vector_type(4)));
typedef __bf16  bf16x2 __attribute__((ext_vector_type(2)));
typedef float   f32x4  __attribute__((ext_vector_type(4)));
typedef unsigned int uint32;

#define HIDDEN 4096
#define NHQ    32
#define NHKV   8
#define HD     128
#define SEQ    2048
#define BATCH  2
#define NTOK   (BATCH * SEQ)
#define KVDIM  (NHKV * HD)   // 1024

#define MBYTE  (1024ull * 1024ull)

// ---------------------------------------------------------------------------
// Helpers
// ---------------------------------------------------------------------------
__device__ inline void load8(const float* p, __bf16* d)
{
    float4 a = *reinterpret_cast<const float4*>(p);
    float4 b = *reinterpret_cast<const float4*>(p + 4);
    d[0] = (__bf16)a.x; d[1] = (__bf16)a.y; d[2] = (__bf16)a.z; d[3] = (__bf16)a.w;
    d[4] = (__bf16)b.x; d[5] = (__bf16)b.y; d[6] = (__bf16)b.z; d[7] = (__bf16)b.w;
}
__device__ inline void load8(const __hip_bfloat16* p, __bf16* d)
{
    *reinterpret_cast<bf16x8*>(d) = *reinterpret_cast<const bf16x8*>(p);
}

__device__ inline void storeC(float* C, size_t idx, float v)          { C[idx] = v; }
__device__ inline void storeC(__hip_bfloat16* C, size_t idx, float v) { C[idx] = __float2bfloat16(v); }

// ---------------------------------------------------------------------------
// Elementwise cast fp32 -> bf16, 8 elems/thread.
// ---------------------------------------------------------------------------
__global__ __launch_bounds__(256) void cast_f2b(
    const float* __restrict__ in, __hip_bfloat16* __restrict__ out, size_t n8)
{
    size_t i = (size_t)blockIdx.x * blockDim.x + threadIdx.x;
    if (i >= n8) return;
    const float* p = in + i * 8;
    float4 a = *reinterpret_cast<const float4*>(p);
    float4 b = *reinterpret_cast<const float4*>(p + 4);
    bf16x8 v;
    v[0] = (__bf16)a.x; v[1] = (__bf16)a.y; v[2] = (__bf16)a.z; v[3] = (__bf16)a.w;
    v[4] = (__bf16)b.x; v[5] = (__bf16)b.y; v[6] = (__bf16)b.z; v[7] = (__bf16)b.w;
    *reinterpret_cast<bf16x8*>(out + i * 8) = v;
}

// ---------------------------------------------------------------------------
// Transpose + cast: W fp32 [K][ldw] -> Wt bf16 [N][K]. 32x32 LDS tiles.
// ---------------------------------------------------------------------------
__global__ __launch_bounds__(256) void transpose_cast(
    const float* __restrict__ W, int ldw,
    __hip_bfloat16* __restrict__ Wt, int K)
{
    __shared__ __align__(16) float tf[32][36];
    const int k0 = blockIdx.x * 32;
    const int n0 = blockIdx.y * 32;
    const int r  = threadIdx.x >> 3;         // 0..31
    const int c4 = (threadIdx.x & 7) * 4;    // 0,4,...,28

    *reinterpret_cast<float4*>(&tf[r][c4]) =
        *reinterpret_cast<const float4*>(W + (size_t)(k0 + r) * ldw + n0 + c4);
    __syncthreads();

    bf16x4 o;
    o[0] = (__bf16)tf[c4 + 0][r]; o[1] = (__bf16)tf[c4 + 1][r];
    o[2] = (__bf16)tf[c4 + 2][r]; o[3] = (__bf16)tf[c4 + 3][r];
    *reinterpret_cast<bf16x4*>(Wt + (size_t)(n0 + r) * K + k0 + c4) = o;
}

// ---------------------------------------------------------------------------
// GEMM, reg-staged 128x128 tile: C = A @ Bt^T. A bf16 [M][K], Bt bf16 [N][K].
// BK=32, 4 waves, each wave 64x64 = 4x4 MFMA 16x16x32.
// Staging: global bf16x8 loads -> ds_write_b128 into linear LDS (no
// global_load_lds; thread t writes bytes [32t,32t+32) of each tile ->
// conflict-free). Fragments via ds_read_b128.
// ---------------------------------------------------------------------------
#define GBM 128
#define GBN 128
#define GBK 32

template <typename TC>
__global__ __launch_bounds__(256) void gemm128r(
    const __hip_bfloat16* __restrict__ A,
    const __hip_bfloat16* __restrict__ Bt,
    TC* __restrict__ C,
    int M, int N, int K, int ldc)
{
    __shared__ __align__(16) __bf16 As[GBM][GBK];   // 8 KB, linear
    __shared__ __align__(16) __bf16 Bs[GBN][GBK];   // 8 KB, linear

    const int tid  = threadIdx.x;
    const int w    = tid >> 6;
    const int lane = tid & 63;
    const int lrow = lane & 15;
    const int lq   = lane >> 4;
    const int bm   = blockIdx.y * GBM;
    const int bn   = blockIdx.x * GBN;
    const int wr   = (w >> 1) * 64;
    const int wc   = (w & 1) * 64;

    const int srow = tid >> 1;            // 0..127 (tile row)
    const int scol = (tid & 1) * 16;      // 0 or 16 (k offset)

    f32x4 acc[4][4] = {};

    const __hip_bfloat16* ga = A  + (size_t)(bm + srow) * K + scol;
    const __hip_bfloat16* gb = Bt + (size_t)(bn + srow) * K + scol;

    for (int k0 = 0; k0 < K; k0 += GBK) {
        bf16x8 a0 = *reinterpret_cast<const bf16x8*>(ga + k0);
        bf16x8 a1 = *reinterpret_cast<const bf16x8*>(ga + k0 + 8);
        bf16x8 b0 = *reinterpret_cast<const bf16x8*>(gb + k0);
        bf16x8 b1 = *reinterpret_cast<const bf16x8*>(gb + k0 + 8);

        *reinterpret_cast<bf16x8*>(&As[srow][scol])     = a0;
        *reinterpret_cast<bf16x8*>(&As[srow][scol + 8]) = a1;
        *reinterpret_cast<bf16x8*>(&Bs[srow][scol])     = b0;
        *reinterpret_cast<bf16x8*>(&Bs[srow][scol + 8]) = b1;

        __syncthreads();

        bf16x8 af[4], bfr[4];
        #pragma unroll
        for (int i = 0; i < 4; ++i) {
            af[i]  = *reinterpret_cast<const bf16x8*>(&As[wr + i * 16 + lrow][lq * 8]);
            bfr[i] = *reinterpret_cast<const bf16x8*>(&Bs[wc + i * 16 + lrow][lq * 8]);
        }
        #pragma unroll
        for (int mi = 0; mi < 4; ++mi)
            #pragma unroll
            for (int ni = 0; ni < 4; ++ni)
                acc[mi][ni] = __builtin_amdgcn_mfma_f32_16x16x32_bf16(
                    af[mi], bfr[ni], acc[mi][ni], 0, 0, 0);

        __syncthreads();
    }

    // Epilogue: D layout col=lane&15, row=(lane>>4)*4+reg
    #pragma unroll
    for (int mi = 0; mi < 4; ++mi)
        #pragma unroll
        for (int ni = 0; ni < 4; ++ni)
            #pragma unroll
            for (int r = 0; r < 4; ++r) {
                int row = bm + wr + mi * 16 + lq * 4 + r;
                int col = bn + wc + ni * 16 + lrow;
                storeC(C, (size_t)row * ldc + col, acc[mi][ni][r]);
            }
}

// ---------------------------------------------------------------------------
// Fallback GEMM (round-2 proven): C = A @ B, fp32/bf16 inputs staged to LDS.
// ---------------------------------------------------------------------------
#define BM 64
#define BN 64
#define BK 32
#define LDSS 40

template <typename TA, typename TB, typename TC>
__global__ __launch_bounds__(256) void gemm_to(
    const TA* __restrict__ A,
    const TB* __restrict__ B,
    TC* __restrict__ C,
    int M, int N, int K)
{
    __shared__ __align__(16) __bf16 As[BM][LDSS];
    __shared__ __align__(16) __bf16 Bs[BN][LDSS];

    const int tid  = threadIdx.x;
    const int bm   = blockIdx.y * BM;
    const int bn   = blockIdx.x * BN;
    const int wave = tid >> 6;
    const int lane = tid & 63;
    const int wr   = (wave >> 1) * 32;
    const int wc   = (wave & 1) * 32;
    const int lrow = lane & 15;
    const int lq   = lane >> 4;

    f32x4 acc[2][2] = {};

    const int ar = tid >> 2;
    const int ac = (tid & 3) * 8;
    const int br = tid >> 3;
    const int bc = (tid & 7) * 8;

    for (int k0 = 0; k0 < K; k0 += BK) {
        __bf16 abuf[8], bbuf[8];
        load8(A + (size_t)(bm + ar) * K + (k0 + ac), abuf);
        load8(B + (size_t)(k0 + br) * N + (bn + bc), bbuf);

        *reinterpret_cast<bf16x8*>(&As[ar][ac]) = *reinterpret_cast<bf16x8*>(abuf);
        #pragma unroll
        for (int j = 0; j < 8; ++j)
            Bs[bc + j][br] = bbuf[j];

        __syncthreads();

        bf16x8 afrag[2], bfrag[2];
        #pragma unroll
        for (int mi = 0; mi < 2; ++mi)
            afrag[mi] = *reinterpret_cast<const bf16x8*>(&As[wr + mi * 16 + lrow][lq * 8]);
        #pragma unroll
        for (int ni = 0; ni < 2; ++ni)
            bfrag[ni] = *reinterpret_cast<const bf16x8*>(&Bs[wc + ni * 16 + lrow][lq * 8]);

        #pragma unroll
        for (int mi = 0; mi < 2; ++mi)
            #pragma unroll
            for (int ni = 0; ni < 2; ++ni)
                acc[mi][ni] = __builtin_amdgcn_mfma_f32_16x16x32_bf16(
                    afrag[mi], bfrag[ni], acc[mi][ni], 0, 0, 0);

        __syncthreads();
    }

    #pragma unroll
    for (int mi = 0; mi < 2; ++mi)
        #pragma unroll
        for (int ni = 0; ni < 2; ++ni)
            #pragma unroll
            for (int r = 0; r < 4; ++r) {
                int row = bm + wr + mi * 16 + lq * 4 + r;
                int col = bn + wc + ni * 16 + lrow;
                storeC(C, (size_t)row * N + col, acc[mi][ni][r]);
            }
}

// ---------------------------------------------------------------------------
// RoPE in-place on bf16.
// ---------------------------------------------------------------------------
__global__ __launch_bounds__(256) void rope_kernel(
    __hip_bfloat16* __restrict__ X, int nh, size_t total)
{
    size_t idx = (size_t)blockIdx.x * blockDim.x + threadIdx.x;
    if (idx >= total) return;
    int    i   = (int)(idx & 63);
    size_t t   = idx >> 6;
    int    h   = (int)(t % nh);
    size_t tok = t / nh;
    int    pos = (int)(tok & (SEQ - 1));

    float inv_freq = exp2f(-(float)i * (13.287712379549449f / 64.0f));
    float fr = (float)pos * inv_freq;
    float sv, cv;
    sincosf(fr, &sv, &cv);

    size_t base = tok * ((size_t)nh * HD) + (size_t)h * HD + i;
    float x1 = __bfloat162float(X[base]);
    float x2 = __bfloat162float(X[base + 64]);
    X[base]      = __float2bfloat16(x1 * cv - x2 * sv);
    X[base + 64] = __float2bfloat16(x2 * cv + x1 * sv);
}

// ---------------------------------------------------------------------------
// V transpose: Vb [b*SEQ + s][KVDIM] -> Vt [b*KVDIM + dg][SEQ]
// ---------------------------------------------------------------------------
__global__ __launch_bounds__(256) void transpose_v(
    const __hip_bfloat16* __restrict__ Vb,
    __hip_bfloat16* __restrict__ Vt)
{
    __shared__ __align__(16) __bf16 t[32][36];
    const int bz = blockIdx.z;
    const int s0 = blockIdx.x * 32;
    const int c0 = blockIdx.y * 32;
    const int r  = threadIdx.x >> 3;
    const int c4 = (threadIdx.x & 7) * 4;

    *reinterpret_cast<bf16x4*>(&t[r][c4]) =
        *reinterpret_cast<const bf16x4*>(Vb + ((size_t)bz * SEQ + s0 + r) * KVDIM + c0 + c4);
    __syncthreads();

    bf16x4 o;
    o[0] = t[c4 + 0][r]; o[1] = t[c4 + 1][r];
    o[2] = t[c4 + 2][r]; o[3] = t[c4 + 3][r];
    *reinterpret_cast<bf16x4*>(Vt + ((size_t)bz * KVDIM + c0 + r) * SEQ + s0 + c4) = o;
}

// ---------------------------------------------------------------------------
// Flash attention with MFMA (verified round 2).
// ---------------------------------------------------------------------------
__global__ __launch_bounds__(256) void attn_mfma(
    const __hip_bfloat16* __restrict__ Qg,   // [NTOK][HIDDEN]
    const __hip_bfloat16* __restrict__ Kg,   // [NTOK][KVDIM]
    const __hip_bfloat16* __restrict__ Vt,   // [B*KVDIM][SEQ]
    __hip_bfloat16* __restrict__ Og)         // [NTOK][HIDDEN] (may alias Qg)
{
    __shared__ __align__(16) __bf16 Pl[4][16][40];
    __shared__ __align__(16) __bf16 Ol[4][16][136];

    const int wv   = threadIdx.x >> 6;
    const int lane = threadIdx.x & 63;
    const int lq   = lane & 15;
    const int g    = lane >> 4;

    const int bid = blockIdx.x;
    const int qt  = 127 - (bid & 127);
    const int khb = bid >> 7;
    const int b   = khb >> 3;
    const int kh  = khb & 7;
    const int qh  = kh * 4 + wv;
    const int q0  = qt * 16;
    const int q_g = q0 + lq;

    const __hip_bfloat16* qrow = Qg + ((size_t)b * SEQ + q0 + lq) * HIDDEN + (size_t)qh * HD;
    bf16x8 qf[4];
#pragma unroll
    for (int dj = 0; dj < 4; ++dj)
        qf[dj] = *reinterpret_cast<const bf16x8*>(qrow + dj * 32 + g * 8);

    const __hip_bfloat16* Kb = Kg + ((size_t)b * SEQ) * KVDIM + (size_t)kh * HD;
    const __hip_bfloat16* Vb = Vt + ((size_t)b * KVDIM + (size_t)kh * HD) * SEQ;

    f32x4 oacc[8] = {};
    float m_run = -INFINITY, l_run = 0.0f;
    const float SCALE = 0.08838834764831845f;

    const int kv_len = q0 + 16;
    for (int k0 = 0; k0 < kv_len; k0 += 32) {
        f32x4 sacc[2] = {};
#pragma unroll
        for (int kt = 0; kt < 2; ++kt) {
            const __hip_bfloat16* krow = Kb + (size_t)(k0 + kt * 16 + lq) * KVDIM;
#pragma unroll
            for (int dj = 0; dj < 4; ++dj) {
                bf16x8 kf = *reinterpret_cast<const bf16x8*>(krow + dj * 32 + g * 8);
                sacc[kt] = __builtin_amdgcn_mfma_f32_16x16x32_bf16(kf, qf[dj], sacc[kt], 0, 0, 0);
            }
        }

        float p[2][4];
        float tmax = -INFINITY;
#pragma unroll
        for (int kt = 0; kt < 2; ++kt)
#pragma unroll
            for (int r = 0; r < 4; ++r) {
                int   k_g = k0 + kt * 16 + 4 * g + r;
                float s   = sacc[kt][r] * SCALE;
                s = (k_g <= q_g) ? s : -INFINITY;
                p[kt][r] = s;
                tmax = fmaxf(tmax, s);
            }
        tmax = fmaxf(tmax, __shfl_xor(tmax, 16));
        tmax = fmaxf(tmax, __shfl_xor(tmax, 32));

        float m_new = fmaxf(m_run, tmax);
        float corr  = __expf(m_run - m_new);
        float tsum  = 0.0f;
#pragma unroll
        for (int kt = 0; kt < 2; ++kt)
#pragma unroll
            for (int r = 0; r < 4; ++r) {
                float e = __expf(p[kt][r] - m_new);
                p[kt][r] = e;
                tsum += e;
            }
        tsum += __shfl_xor(tsum, 16);
        tsum += __shfl_xor(tsum, 32);
        l_run = l_run * corr + tsum;
        m_run = m_new;

#pragma unroll
        for (int kt = 0; kt < 2; ++kt) {
            bf16x2 lo, hi;
            lo[0] = (__bf16)p[kt][0]; lo[1] = (__bf16)p[kt][1];
            hi[0] = (__bf16)p[kt][2]; hi[1] = (__bf16)p[kt][3];
            *reinterpret_cast<bf16x2*>(&Pl[wv][lq][kt * 16 + 4 * g])     = lo;
            *reinterpret_cast<bf16x2*>(&Pl[wv][lq][kt * 16 + 4 * g + 2]) = hi;
        }
        bf16x8 pf = *reinterpret_cast<const bf16x8*>(&Pl[wv][lq][8 * g]);

#pragma unroll
        for (int dt = 0; dt < 8; ++dt) {
            oacc[dt][0] *= corr; oacc[dt][1] *= corr;
            oacc[dt][2] *= corr; oacc[dt][3] *= corr;
        }
#pragma unroll
        for (int dt = 0; dt < 8; ++dt) {
            bf16x8 vf = *reinterpret_cast<const bf16x8*>(
                Vb + (size_t)(dt * 16 + lq) * SEQ + k0 + 8 * g);
            oacc[dt] = __builtin_amdgcn_mfma_f32_16x16x32_bf16(vf, pf, oacc[dt], 0, 0, 0);
        }
    }

    float inv = 1.0f / l_run;
#pragma unroll
    for (int dt = 0; dt < 8; ++dt) {
        bf16x2 lo, hi;
        lo[0] = (__bf16)(oacc[dt][0] * inv); lo[1] = (__bf16)(oacc[dt][1] * inv);
        hi[0] = (__bf16)(oacc[dt][2] * inv); hi[1] = (__bf16)(oacc[dt][3] * inv);
        *reinterpret_cast<bf16x2*>(&Ol[wv][lq][dt * 16 + 4 * g])     = lo;
        *reinterpret_cast<bf16x2*>(&Ol[wv][lq][dt * 16 + 4 * g + 2]) = hi;
    }

    __hip_bfloat16* orow = Og + ((size_t)b * SEQ + q0 + lq) * HIDDEN + (size_t)qh * HD;
#pragma unroll
    for (int j = 0; j < 4; ++j) {
        int c = j * 4 + g;
        bf16x8 v = *reinterpret_cast<const bf16x8*>(&Ol[wv][lq][c * 8]);
        *reinterpret_cast<bf16x8*>(orow + c * 8) = v;
    }
}

// ---------------------------------------------------------------------------
// Orchestration. Two paths:
//  FAST (ws_size >= 112 MB): all scratch in ws, d_out written once (fp32 out).
//    ws: Qb[0:32M] Kb[32:40M] Vb[40:48M] xb[48:80M] Wt[80:112M]
//        Vt[48:56M] overlays xb after xb is dead (post V-GEMM).
//  FALLBACK (else): byte-identical round-2 proven path (fp32-input gemm_to).
// ---------------------------------------------------------------------------
extern "C" void kernel_launch(void* const* d_in, const int* in_sizes, int n_in,
                              void* d_out, int out_size, void* d_ws, size_t ws_size,
                              hipStream_t stream)
{
    const float* x  = (const float*)d_in[0];
    const float* Wq = (const float*)d_in[1];
    const float* Wk = (const float*)d_in[2];
    const float* Wv = (const float*)d_in[3];
    const float* Wo = (const float*)d_in[4];
    float* out = (float*)d_out;

    char* ws = (char*)d_ws;
    dim3 blk(256);

    if (ws_size >= 112 * MBYTE) {
        // ---------------- FAST PATH: scratch entirely in workspace ----------
        __hip_bfloat16* Qb = (__hip_bfloat16*)(ws +  0 * MBYTE);
        __hip_bfloat16* Kb = (__hip_bfloat16*)(ws + 32 * MBYTE);
        __hip_bfloat16* Vb = (__hip_bfloat16*)(ws + 40 * MBYTE);
        __hip_bfloat16* xb = (__hip_bfloat16*)(ws + 48 * MBYTE);
        __hip_bfloat16* Vt = (__hip_bfloat16*)(ws + 48 * MBYTE);   // overlays dead xb
        __hip_bfloat16* Wt = (__hip_bfloat16*)(ws + 80 * MBYTE);

        cast_f2b<<<(NTOK * HIDDEN / 8 + 255) / 256, blk, 0, stream>>>(
            x, xb, (size_t)NTOK * HIDDEN / 8);

        // Q = xb @ Wq
        transpose_cast<<<dim3(HIDDEN / 32, HIDDEN / 32), blk, 0, stream>>>(Wq, HIDDEN, Wt, HIDDEN);
        gemm128r<__hip_bfloat16><<<dim3(HIDDEN / GBN, NTOK / GBM), blk, 0, stream>>>(
            xb, Wt, Qb, NTOK, HIDDEN, HIDDEN, HIDDEN);

        // K = xb @ Wk
        transpose_cast<<<dim3(HIDDEN / 32, KVDIM / 32), blk, 0, stream>>>(Wk, KVDIM, Wt, HIDDEN);
        gemm128r<__hip_bfloat16><<<dim3(KVDIM / GBN, NTOK / GBM), blk, 0, stream>>>(
            xb, Wt, Kb, NTOK, KVDIM, HIDDEN, KVDIM);

        // V = xb @ Wv  (last consumer of xb)
        transpose_cast<<<dim3(HIDDEN / 32, KVDIM / 32), blk, 0, stream>>>(Wv, KVDIM, Wt, HIDDEN);
        gemm128r<__hip_bfloat16><<<dim3(KVDIM / GBN, NTOK / GBM), blk, 0, stream>>>(
            xb, Wt, Vb, NTOK, KVDIM, HIDDEN, KVDIM);

        // RoPE in place
        {
            size_t totq = (size_t)NTOK * NHQ * 64;
            size_t totk = (size_t)NTOK * NHKV * 64;
            rope_kernel<<<(unsigned)((totq + 255) / 256), blk, 0, stream>>>(Qb, NHQ,  totq);
            rope_kernel<<<(unsigned)((totk + 255) / 256), blk, 0, stream>>>(Kb, NHKV, totk);
        }

        // V^T over dead xb region
        transpose_v<<<dim3(SEQ / 32, KVDIM / 32, BATCH), blk, 0, stream>>>(Vb, Vt);

        attn_mfma<<<BATCH * NHKV * (SEQ / 16), blk, 0, stream>>>(Qb, Kb, Vt, Qb);

        // out = O @ Wo (full Wo^T fits in Wt region)
        transpose_cast<<<dim3(HIDDEN / 32, HIDDEN / 32), blk, 0, stream>>>(Wo, HIDDEN, Wt, HIDDEN);
        gemm128r<float><<<dim3(HIDDEN / GBN, NTOK / GBM), blk, 0, stream>>>(
            Qb, Wt, out, NTOK, HIDDEN, HIDDEN, HIDDEN);
    } else {
        // ---------------- FALLBACK: round-2 proven path ---------------------
        __hip_bfloat16* Qb = (__hip_bfloat16*)ws;
        __hip_bfloat16* Kb = (__hip_bfloat16*)(ws + (size_t)NTOK * HIDDEN * 2);
        __hip_bfloat16* Vb = (__hip_bfloat16*)(ws + (size_t)NTOK * HIDDEN * 2
                                                  + (size_t)NTOK * KVDIM * 2);

        const size_t base_ws  = (size_t)NTOK * HIDDEN * 2 + 2 * (size_t)NTOK * KVDIM * 2;
        const size_t vt_bytes = (size_t)NTOK * KVDIM * 2;
        __hip_bfloat16* Vtr = (ws_size >= base_ws + vt_bytes)
                            ? (__hip_bfloat16*)(ws + base_ws)
                            : (__hip_bfloat16*)d_out;

        gemm_to<float, float, __hip_bfloat16><<<dim3(HIDDEN / BN, NTOK / BM), blk, 0, stream>>>(
            x, Wq, Qb, NTOK, HIDDEN, HIDDEN);
        gemm_to<float, float, __hip_bfloat16><<<dim3(KVDIM / BN, NTOK / BM), blk, 0, stream>>>(
            x, Wk, Kb, NTOK, KVDIM, HIDDEN);
        gemm_to<float, float, __hip_bfloat16><<<dim3(KVDIM / BN, NTOK / BM), blk, 0, stream>>>(
            x, Wv, Vb, NTOK, KVDIM, HIDDEN);

        {
            size_t totq = (size_t)NTOK * NHQ * 64;
            size_t totk = (size_t)NTOK * NHKV * 64;
            rope_kernel<<<(unsigned)((totq + 255) / 256), blk, 0, stream>>>(Qb, NHQ,  totq);
            rope_kernel<<<(unsigned)((totk + 255) / 256), blk, 0, stream>>>(Kb, NHKV, totk);
        }

        transpose_v<<<dim3(SEQ / 32, KVDIM / 32, BATCH), blk, 0, stream>>>(Vb, Vtr);

        attn_mfma<<<BATCH * NHKV * (SEQ / 16), blk, 0, stream>>>(Qb, Kb, Vtr, Qb);

        gemm_to<__hip_bfloat16, float, float><<<dim3(HIDDEN / BN, NTOK / BM), blk, 0, stream>>>(
            Qb, Wo, out, NTOK, HIDDEN, HIDDEN);
    }
}

// Round 6
// 1516.468 us; speedup vs baseline: 6.8665x; 1.0137x over previous
//
#include <hip/hip_runtime.h>
#include <hip/hip_bf16.h>
#include <math.h>

typedef __bf16  bf16x8 __attribute__((ext_vector_type(8)));
typedef __bf16  bf16x4 __attribute__((ext_vector_type(4)));
typedef __bf16  bf16x2 __attribute__((ext_vector_type(2)));
typedef float   f32x4  __attribute__((ext_vector_type(4)));
typedef unsigned int uint32;

#define HIDDEN 4096
#define NHQ    32
#define NHKV   8
#define HD     128
#define SEQ    2048
#define BATCH  2
#define NTOK   (BATCH * SEQ)
#define KVDIM  (NHKV * HD)   // 1024

#define MBYTE  (1024ull * 1024ull)

// ---------------------------------------------------------------------------
// Helpers
// ---------------------------------------------------------------------------
__device__ inline void load8(const float* p, __bf16* d)
{
    float4 a = *reinterpret_cast<const float4*>(p);
    float4 b = *reinterpret_cast<const float4*>(p + 4);
    d[0] = (__bf16)a.x; d[1] = (__bf16)a.y; d[2] = (__bf16)a.z; d[3] = (__bf16)a.w;
    d[4] = (__bf16)b.x; d[5] = (__bf16)b.y; d[6] = (__bf16)b.z; d[7] = (__bf16)b.w;
}
__device__ inline void load8(const __hip_bfloat16* p, __bf16* d)
{
    *reinterpret_cast<bf16x8*>(d) = *reinterpret_cast<const bf16x8*>(p);
}

__device__ inline void storeC(float* C, size_t idx, float v)          { C[idx] = v; }
__device__ inline void storeC(__hip_bfloat16* C, size_t idx, float v) { C[idx] = __float2bfloat16(v); }

// ---------------------------------------------------------------------------
// Elementwise cast fp32 -> bf16, 8 elems/thread.
// ---------------------------------------------------------------------------
__global__ __launch_bounds__(256) void cast_f2b(
    const float* __restrict__ in, __hip_bfloat16* __restrict__ out, size_t n8)
{
    size_t i = (size_t)blockIdx.x * blockDim.x + threadIdx.x;
    if (i >= n8) return;
    const float* p = in + i * 8;
    float4 a = *reinterpret_cast<const float4*>(p);
    float4 b = *reinterpret_cast<const float4*>(p + 4);
    bf16x8 v;
    v[0] = (__bf16)a.x; v[1] = (__bf16)a.y; v[2] = (__bf16)a.z; v[3] = (__bf16)a.w;
    v[4] = (__bf16)b.x; v[5] = (__bf16)b.y; v[6] = (__bf16)b.z; v[7] = (__bf16)b.w;
    *reinterpret_cast<bf16x8*>(out + i * 8) = v;
}

// ---------------------------------------------------------------------------
// Transpose + cast: W fp32 [K][ldw] -> Wt bf16 [N][K]. 32x32 LDS tiles.
// ---------------------------------------------------------------------------
__global__ __launch_bounds__(256) void transpose_cast(
    const float* __restrict__ W, int ldw,
    __hip_bfloat16* __restrict__ Wt, int K)
{
    __shared__ __align__(16) float tf[32][36];
    const int k0 = blockIdx.x * 32;
    const int n0 = blockIdx.y * 32;
    const int r  = threadIdx.x >> 3;         // 0..31
    const int c4 = (threadIdx.x & 7) * 4;    // 0,4,...,28

    *reinterpret_cast<float4*>(&tf[r][c4]) =
        *reinterpret_cast<const float4*>(W + (size_t)(k0 + r) * ldw + n0 + c4);
    __syncthreads();

    bf16x4 o;
    o[0] = (__bf16)tf[c4 + 0][r]; o[1] = (__bf16)tf[c4 + 1][r];
    o[2] = (__bf16)tf[c4 + 2][r]; o[3] = (__bf16)tf[c4 + 3][r];
    *reinterpret_cast<bf16x4*>(Wt + (size_t)(n0 + r) * K + k0 + c4) = o;
}

// ---------------------------------------------------------------------------
// GEMM, reg-staged 128x128 tile: C = A @ Bt^T. A bf16 [M][K], Bt bf16 [N][K].
// BK=32, 4 waves, each wave 64x64 = 4x4 MFMA 16x16x32.  (verified round 5)
// ---------------------------------------------------------------------------
#define GBM 128
#define GBN 128
#define GBK 32

template <typename TC>
__global__ __launch_bounds__(256) void gemm128r(
    const __hip_bfloat16* __restrict__ A,
    const __hip_bfloat16* __restrict__ Bt,
    TC* __restrict__ C,
    int M, int N, int K, int ldc)
{
    __shared__ __align__(16) __bf16 As[GBM][GBK];   // 8 KB, linear
    __shared__ __align__(16) __bf16 Bs[GBN][GBK];   // 8 KB, linear

    const int tid  = threadIdx.x;
    const int w    = tid >> 6;
    const int lane = tid & 63;
    const int lrow = lane & 15;
    const int lq   = lane >> 4;
    const int bm   = blockIdx.y * GBM;
    const int bn   = blockIdx.x * GBN;
    const int wr   = (w >> 1) * 64;
    const int wc   = (w & 1) * 64;

    const int srow = tid >> 1;            // 0..127 (tile row)
    const int scol = (tid & 1) * 16;      // 0 or 16 (k offset)

    f32x4 acc[4][4] = {};

    const __hip_bfloat16* ga = A  + (size_t)(bm + srow) * K + scol;
    const __hip_bfloat16* gb = Bt + (size_t)(bn + srow) * K + scol;

    for (int k0 = 0; k0 < K; k0 += GBK) {
        bf16x8 a0 = *reinterpret_cast<const bf16x8*>(ga + k0);
        bf16x8 a1 = *reinterpret_cast<const bf16x8*>(ga + k0 + 8);
        bf16x8 b0 = *reinterpret_cast<const bf16x8*>(gb + k0);
        bf16x8 b1 = *reinterpret_cast<const bf16x8*>(gb + k0 + 8);

        *reinterpret_cast<bf16x8*>(&As[srow][scol])     = a0;
        *reinterpret_cast<bf16x8*>(&As[srow][scol + 8]) = a1;
        *reinterpret_cast<bf16x8*>(&Bs[srow][scol])     = b0;
        *reinterpret_cast<bf16x8*>(&Bs[srow][scol + 8]) = b1;

        __syncthreads();

        bf16x8 af[4], bfr[4];
        #pragma unroll
        for (int i = 0; i < 4; ++i) {
            af[i]  = *reinterpret_cast<const bf16x8*>(&As[wr + i * 16 + lrow][lq * 8]);
            bfr[i] = *reinterpret_cast<const bf16x8*>(&Bs[wc + i * 16 + lrow][lq * 8]);
        }
        #pragma unroll
        for (int mi = 0; mi < 4; ++mi)
            #pragma unroll
            for (int ni = 0; ni < 4; ++ni)
                acc[mi][ni] = __builtin_amdgcn_mfma_f32_16x16x32_bf16(
                    af[mi], bfr[ni], acc[mi][ni], 0, 0, 0);

        __syncthreads();
    }

    // Epilogue: D layout col=lane&15, row=(lane>>4)*4+reg
    #pragma unroll
    for (int mi = 0; mi < 4; ++mi)
        #pragma unroll
        for (int ni = 0; ni < 4; ++ni)
            #pragma unroll
            for (int r = 0; r < 4; ++r) {
                int row = bm + wr + mi * 16 + lq * 4 + r;
                int col = bn + wc + ni * 16 + lrow;
                storeC(C, (size_t)row * ldc + col, acc[mi][ni][r]);
            }
}

// ---------------------------------------------------------------------------
// Fallback GEMM (round-2 proven): C = A @ B, fp32/bf16 inputs staged to LDS.
// ---------------------------------------------------------------------------
#define BM 64
#define BN 64
#define BK 32
#define LDSS 40

template <typename TA, typename TB, typename TC>
__global__ __launch_bounds__(256) void gemm_to(
    const TA* __restrict__ A,
    const TB* __restrict__ B,
    TC* __restrict__ C,
    int M, int N, int K)
{
    __shared__ __align__(16) __bf16 As[BM][LDSS];
    __shared__ __align__(16) __bf16 Bs[BN][LDSS];

    const int tid  = threadIdx.x;
    const int bm   = blockIdx.y * BM;
    const int bn   = blockIdx.x * BN;
    const int wave = tid >> 6;
    const int lane = tid & 63;
    const int wr   = (wave >> 1) * 32;
    const int wc   = (wave & 1) * 32;
    const int lrow = lane & 15;
    const int lq   = lane >> 4;

    f32x4 acc[2][2] = {};

    const int ar = tid >> 2;
    const int ac = (tid & 3) * 8;
    const int br = tid >> 3;
    const int bc = (tid & 7) * 8;

    for (int k0 = 0; k0 < K; k0 += BK) {
        __bf16 abuf[8], bbuf[8];
        load8(A + (size_t)(bm + ar) * K + (k0 + ac), abuf);
        load8(B + (size_t)(k0 + br) * N + (bn + bc), bbuf);

        *reinterpret_cast<bf16x8*>(&As[ar][ac]) = *reinterpret_cast<bf16x8*>(abuf);
        #pragma unroll
        for (int j = 0; j < 8; ++j)
            Bs[bc + j][br] = bbuf[j];

        __syncthreads();

        bf16x8 afrag[2], bfrag[2];
        #pragma unroll
        for (int mi = 0; mi < 2; ++mi)
            afrag[mi] = *reinterpret_cast<const bf16x8*>(&As[wr + mi * 16 + lrow][lq * 8]);
        #pragma unroll
        for (int ni = 0; ni < 2; ++ni)
            bfrag[ni] = *reinterpret_cast<const bf16x8*>(&Bs[wc + ni * 16 + lrow][lq * 8]);

        #pragma unroll
        for (int mi = 0; mi < 2; ++mi)
            #pragma unroll
            for (int ni = 0; ni < 2; ++ni)
                acc[mi][ni] = __builtin_amdgcn_mfma_f32_16x16x32_bf16(
                    afrag[mi], bfrag[ni], acc[mi][ni], 0, 0, 0);

        __syncthreads();
    }

    #pragma unroll
    for (int mi = 0; mi < 2; ++mi)
        #pragma unroll
        for (int ni = 0; ni < 2; ++ni)
            #pragma unroll
            for (int r = 0; r < 4; ++r) {
                int row = bm + wr + mi * 16 + lq * 4 + r;
                int col = bn + wc + ni * 16 + lrow;
                storeC(C, (size_t)row * N + col, acc[mi][ni][r]);
            }
}

// ---------------------------------------------------------------------------
// RoPE in-place on bf16.
// ---------------------------------------------------------------------------
__global__ __launch_bounds__(256) void rope_kernel(
    __hip_bfloat16* __restrict__ X, int nh, size_t total)
{
    size_t idx = (size_t)blockIdx.x * blockDim.x + threadIdx.x;
    if (idx >= total) return;
    int    i   = (int)(idx & 63);
    size_t t   = idx >> 6;
    int    h   = (int)(t % nh);
    size_t tok = t / nh;
    int    pos = (int)(tok & (SEQ - 1));

    float inv_freq = exp2f(-(float)i * (13.287712379549449f / 64.0f));
    float fr = (float)pos * inv_freq;
    float sv, cv;
    sincosf(fr, &sv, &cv);

    size_t base = tok * ((size_t)nh * HD) + (size_t)h * HD + i;
    float x1 = __bfloat162float(X[base]);
    float x2 = __bfloat162float(X[base + 64]);
    X[base]      = __float2bfloat16(x1 * cv - x2 * sv);
    X[base + 64] = __float2bfloat16(x2 * cv + x1 * sv);
}

// ---------------------------------------------------------------------------
// V transpose: Vb [b*SEQ + s][KVDIM] -> Vt [b*KVDIM + dg][SEQ]
// ---------------------------------------------------------------------------
__global__ __launch_bounds__(256) void transpose_v(
    const __hip_bfloat16* __restrict__ Vb,
    __hip_bfloat16* __restrict__ Vt)
{
    __shared__ __align__(16) __bf16 t[32][36];
    const int bz = blockIdx.z;
    const int s0 = blockIdx.x * 32;
    const int c0 = blockIdx.y * 32;
    const int r  = threadIdx.x >> 3;
    const int c4 = (threadIdx.x & 7) * 4;

    *reinterpret_cast<bf16x4*>(&t[r][c4]) =
        *reinterpret_cast<const bf16x4*>(Vb + ((size_t)bz * SEQ + s0 + r) * KVDIM + c0 + c4);
    __syncthreads();

    bf16x4 o;
    o[0] = t[c4 + 0][r]; o[1] = t[c4 + 1][r];
    o[2] = t[c4 + 2][r]; o[3] = t[c4 + 3][r];
    *reinterpret_cast<bf16x4*>(Vt + ((size_t)bz * KVDIM + c0 + r) * SEQ + s0 + c4) = o;
}

// ---------------------------------------------------------------------------
// Flash attention with MFMA — register-pipelined version.
// One wave = 16 query rows of one q-head; block = 4 waves = the 4 q-heads of
// one KV head. No barriers. Per 32-key tile:
//   - V fragments issued at iteration top (latency hides under QK+softmax)
//   - QK^T uses K fragments prefetched in the PREVIOUS iteration
//   - next K tile issued right after QK MFMAs (hides under softmax+PV)
//   - softmax -> P LDS turnaround -> PV (V already arrived)
// ---------------------------------------------------------------------------
__global__ __launch_bounds__(256) void attn_mfma(
    const __hip_bfloat16* __restrict__ Qg,   // [NTOK][HIDDEN]
    const __hip_bfloat16* __restrict__ Kg,   // [NTOK][KVDIM]
    const __hip_bfloat16* __restrict__ Vt,   // [B*KVDIM][SEQ]
    __hip_bfloat16* __restrict__ Og)         // [NTOK][HIDDEN] (may alias Qg)
{
    __shared__ __align__(16) __bf16 Pl[4][16][40];
    __shared__ __align__(16) __bf16 Ol[4][16][136];

    const int wv   = threadIdx.x >> 6;
    const int lane = threadIdx.x & 63;
    const int lq   = lane & 15;
    const int g    = lane >> 4;

    const int bid = blockIdx.x;
    const int qt  = 127 - (bid & 127);       // heavy q-tiles dispatched first
    const int khb = bid >> 7;
    const int b   = khb >> 3;
    const int kh  = khb & 7;
    const int qh  = kh * 4 + wv;
    const int q0  = qt * 16;
    const int q_g = q0 + lq;

    const __hip_bfloat16* qrow = Qg + ((size_t)b * SEQ + q0 + lq) * HIDDEN + (size_t)qh * HD;
    bf16x8 qf[4];
#pragma unroll
    for (int dj = 0; dj < 4; ++dj)
        qf[dj] = *reinterpret_cast<const bf16x8*>(qrow + dj * 32 + g * 8);

    const __hip_bfloat16* Kb = Kg + ((size_t)b * SEQ) * KVDIM + (size_t)kh * HD;
    const __hip_bfloat16* Vb = Vt + ((size_t)b * KVDIM + (size_t)kh * HD) * SEQ;

    f32x4 oacc[8] = {};
    float m_run = -INFINITY, l_run = 0.0f;
    const float SCALE = 0.08838834764831845f;   // 1/sqrt(128)

    const int kv_len = q0 + 16;

    // Prologue: K tile 0 into registers.
    bf16x8 kreg[8];
#pragma unroll
    for (int kt = 0; kt < 2; ++kt)
#pragma unroll
        for (int dj = 0; dj < 4; ++dj)
            kreg[kt * 4 + dj] = *reinterpret_cast<const bf16x8*>(
                Kb + (size_t)(kt * 16 + lq) * KVDIM + dj * 32 + g * 8);

    for (int k0 = 0; k0 < kv_len; k0 += 32) {
        // ---- V fragments for this tile: issue first, consume in PV.
        bf16x8 vreg[8];
#pragma unroll
        for (int dt = 0; dt < 8; ++dt)
            vreg[dt] = *reinterpret_cast<const bf16x8*>(
                Vb + (size_t)(dt * 16 + lq) * SEQ + k0 + 8 * g);

        // ---- S^T = K · Q^T with resident kreg
        f32x4 sacc[2] = {};
        __builtin_amdgcn_s_setprio(1);
#pragma unroll
        for (int kt = 0; kt < 2; ++kt)
#pragma unroll
            for (int dj = 0; dj < 4; ++dj)
                sacc[kt] = __builtin_amdgcn_mfma_f32_16x16x32_bf16(
                    kreg[kt * 4 + dj], qf[dj], sacc[kt], 0, 0, 0);
        __builtin_amdgcn_s_setprio(0);

        // ---- prefetch next K tile (uniform branch; latency hides under
        //      softmax + PV of this tile)
        if (k0 + 32 < kv_len) {
#pragma unroll
            for (int kt = 0; kt < 2; ++kt)
#pragma unroll
                for (int dj = 0; dj < 4; ++dj)
                    kreg[kt * 4 + dj] = *reinterpret_cast<const bf16x8*>(
                        Kb + (size_t)(k0 + 32 + kt * 16 + lq) * KVDIM + dj * 32 + g * 8);
        }

        // ---- scale + causal mask + tile max (per q-column)
        float p[2][4];
        float tmax = -INFINITY;
#pragma unroll
        for (int kt = 0; kt < 2; ++kt)
#pragma unroll
            for (int r = 0; r < 4; ++r) {
                int   k_g = k0 + kt * 16 + 4 * g + r;
                float s   = sacc[kt][r] * SCALE;
                s = (k_g <= q_g) ? s : -INFINITY;
                p[kt][r] = s;
                tmax = fmaxf(tmax, s);
            }
        tmax = fmaxf(tmax, __shfl_xor(tmax, 16));
        tmax = fmaxf(tmax, __shfl_xor(tmax, 32));

        float m_new = fmaxf(m_run, tmax);
        float corr  = __expf(m_run - m_new);     // 0 on first tile
        float tsum  = 0.0f;
#pragma unroll
        for (int kt = 0; kt < 2; ++kt)
#pragma unroll
            for (int r = 0; r < 4; ++r) {
                float e = __expf(p[kt][r] - m_new);   // masked -> 0
                p[kt][r] = e;
                tsum += e;
            }

        // ---- P -> bf16 LDS turnaround (write first, shuffle-reduce while
        //      the ds_write completes, then read back)
#pragma unroll
        for (int kt = 0; kt < 2; ++kt) {
            bf16x2 lo, hi;
            lo[0] = (__bf16)p[kt][0]; lo[1] = (__bf16)p[kt][1];
            hi[0] = (__bf16)p[kt][2]; hi[1] = (__bf16)p[kt][3];
            *reinterpret_cast<bf16x2*>(&Pl[wv][lq][kt * 16 + 4 * g])     = lo;
            *reinterpret_cast<bf16x2*>(&Pl[wv][lq][kt * 16 + 4 * g + 2]) = hi;
        }

        tsum += __shfl_xor(tsum, 16);
        tsum += __shfl_xor(tsum, 32);
        l_run = l_run * corr + tsum;
        m_run = m_new;

        bf16x8 pf = *reinterpret_cast<const bf16x8*>(&Pl[wv][lq][8 * g]);

        // ---- rescale accumulator, then O^T += V^T · P^T (vreg resident)
#pragma unroll
        for (int dt = 0; dt < 8; ++dt) {
            oacc[dt][0] *= corr; oacc[dt][1] *= corr;
            oacc[dt][2] *= corr; oacc[dt][3] *= corr;
        }
        __builtin_amdgcn_s_setprio(1);
#pragma unroll
        for (int dt = 0; dt < 8; ++dt)
            oacc[dt] = __builtin_amdgcn_mfma_f32_16x16x32_bf16(
                vreg[dt], pf, oacc[dt], 0, 0, 0);
        __builtin_amdgcn_s_setprio(0);
    }

    // ---- epilogue: normalize, transpose O^T -> Ol[q][d] in LDS, coalesced store
    float inv = 1.0f / l_run;
#pragma unroll
    for (int dt = 0; dt < 8; ++dt) {
        bf16x2 lo, hi;
        lo[0] = (__bf16)(oacc[dt][0] * inv); lo[1] = (__bf16)(oacc[dt][1] * inv);
        hi[0] = (__bf16)(oacc[dt][2] * inv); hi[1] = (__bf16)(oacc[dt][3] * inv);
        *reinterpret_cast<bf16x2*>(&Ol[wv][lq][dt * 16 + 4 * g])     = lo;
        *reinterpret_cast<bf16x2*>(&Ol[wv][lq][dt * 16 + 4 * g + 2]) = hi;
    }

    __hip_bfloat16* orow = Og + ((size_t)b * SEQ + q0 + lq) * HIDDEN + (size_t)qh * HD;
#pragma unroll
    for (int j = 0; j < 4; ++j) {
        int c = j * 4 + g;
        bf16x8 v = *reinterpret_cast<const bf16x8*>(&Ol[wv][lq][c * 8]);
        *reinterpret_cast<bf16x8*>(orow + c * 8) = v;
    }
}

// ---------------------------------------------------------------------------
// Orchestration. Two paths:
//  FAST (ws_size >= 112 MB): all scratch in ws, d_out written once (fp32 out).
//    ws: Qb[0:32M] Kb[32:40M] Vb[40:48M] xb[48:80M] Wt[80:112M]
//        Vt[48:56M] overlays xb after xb is dead (post V-GEMM).
//  FALLBACK (else): round-2 proven path (fp32-input gemm_to).
// ---------------------------------------------------------------------------
extern "C" void kernel_launch(void* const* d_in, const int* in_sizes, int n_in,
                              void* d_out, int out_size, void* d_ws, size_t ws_size,
                              hipStream_t stream)
{
    const float* x  = (const float*)d_in[0];
    const float* Wq = (const float*)d_in[1];
    const float* Wk = (const float*)d_in[2];
    const float* Wv = (const float*)d_in[3];
    const float* Wo = (const float*)d_in[4];
    float* out = (float*)d_out;

    char* ws = (char*)d_ws;
    dim3 blk(256);

    if (ws_size >= 112 * MBYTE) {
        // ---------------- FAST PATH: scratch entirely in workspace ----------
        __hip_bfloat16* Qb = (__hip_bfloat16*)(ws +  0 * MBYTE);
        __hip_bfloat16* Kb = (__hip_bfloat16*)(ws + 32 * MBYTE);
        __hip_bfloat16* Vb = (__hip_bfloat16*)(ws + 40 * MBYTE);
        __hip_bfloat16* xb = (__hip_bfloat16*)(ws + 48 * MBYTE);
        __hip_bfloat16* Vt = (__hip_bfloat16*)(ws + 48 * MBYTE);   // overlays dead xb
        __hip_bfloat16* Wt = (__hip_bfloat16*)(ws + 80 * MBYTE);

        cast_f2b<<<(NTOK * HIDDEN / 8 + 255) / 256, blk, 0, stream>>>(
            x, xb, (size_t)NTOK * HIDDEN / 8);

        // Q = xb @ Wq
        transpose_cast<<<dim3(HIDDEN / 32, HIDDEN / 32), blk, 0, stream>>>(Wq, HIDDEN, Wt, HIDDEN);
        gemm128r<__hip_bfloat16><<<dim3(HIDDEN / GBN, NTOK / GBM), blk, 0, stream>>>(
            xb, Wt, Qb, NTOK, HIDDEN, HIDDEN, HIDDEN);

        // K = xb @ Wk
        transpose_cast<<<dim3(HIDDEN / 32, KVDIM / 32), blk, 0, stream>>>(Wk, KVDIM, Wt, HIDDEN);
        gemm128r<__hip_bfloat16><<<dim3(KVDIM / GBN, NTOK / GBM), blk, 0, stream>>>(
            xb, Wt, Kb, NTOK, KVDIM, HIDDEN, KVDIM);

        // V = xb @ Wv  (last consumer of xb)
        transpose_cast<<<dim3(HIDDEN / 32, KVDIM / 32), blk, 0, stream>>>(Wv, KVDIM, Wt, HIDDEN);
        gemm128r<__hip_bfloat16><<<dim3(KVDIM / GBN, NTOK / GBM), blk, 0, stream>>>(
            xb, Wt, Vb, NTOK, KVDIM, HIDDEN, KVDIM);

        // RoPE in place
        {
            size_t totq = (size_t)NTOK * NHQ * 64;
            size_t totk = (size_t)NTOK * NHKV * 64;
            rope_kernel<<<(unsigned)((totq + 255) / 256), blk, 0, stream>>>(Qb, NHQ,  totq);
            rope_kernel<<<(unsigned)((totk + 255) / 256), blk, 0, stream>>>(Kb, NHKV, totk);
        }

        // V^T over dead xb region
        transpose_v<<<dim3(SEQ / 32, KVDIM / 32, BATCH), blk, 0, stream>>>(Vb, Vt);

        attn_mfma<<<BATCH * NHKV * (SEQ / 16), blk, 0, stream>>>(Qb, Kb, Vt, Qb);

        // out = O @ Wo (full Wo^T fits in Wt region)
        transpose_cast<<<dim3(HIDDEN / 32, HIDDEN / 32), blk, 0, stream>>>(Wo, HIDDEN, Wt, HIDDEN);
        gemm128r<float><<<dim3(HIDDEN / GBN, NTOK / GBM), blk, 0, stream>>>(
            Qb, Wt, out, NTOK, HIDDEN, HIDDEN, HIDDEN);
    } else {
        // ---------------- FALLBACK: round-2 proven path ---------------------
        __hip_bfloat16* Qb = (__hip_bfloat16*)ws;
        __hip_bfloat16* Kb = (__hip_bfloat16*)(ws + (size_t)NTOK * HIDDEN * 2);
        __hip_bfloat16* Vb = (__hip_bfloat16*)(ws + (size_t)NTOK * HIDDEN * 2
                                                  + (size_t)NTOK * KVDIM * 2);

        const size_t base_ws  = (size_t)NTOK * HIDDEN * 2 + 2 * (size_t)NTOK * KVDIM * 2;
        const size_t vt_bytes = (size_t)NTOK * KVDIM * 2;
        __hip_bfloat16* Vtr = (ws_size >= base_ws + vt_bytes)
                            ? (__hip_bfloat16*)(ws + base_ws)
                            : (__hip_bfloat16*)d_out;

        gemm_to<float, float, __hip_bfloat16><<<dim3(HIDDEN / BN, NTOK / BM), blk, 0, stream>>>(
            x, Wq, Qb, NTOK, HIDDEN, HIDDEN);
        gemm_to<float, float, __hip_bfloat16><<<dim3(KVDIM / BN, NTOK / BM), blk, 0, stream>>>(
            x, Wk, Kb, NTOK, KVDIM, HIDDEN);
        gemm_to<float, float, __hip_bfloat16><<<dim3(KVDIM / BN, NTOK / BM), blk, 0, stream>>>(
            x, Wv, Vb, NTOK, KVDIM, HIDDEN);

        {
            size_t totq = (size_t)NTOK * NHQ * 64;
            size_t totk = (size_t)NTOK * NHKV * 64;
            rope_kernel<<<(unsigned)((totq + 255) / 256), blk, 0, stream>>>(Qb, NHQ,  totq);
            rope_kernel<<<(unsigned)((totk + 255) / 256), blk, 0, stream>>>(Kb, NHKV, totk);
        }

        transpose_v<<<dim3(SEQ / 32, KVDIM / 32, BATCH), blk, 0, stream>>>(Vb, Vtr);

        attn_mfma<<<BATCH * NHKV * (SEQ / 16), blk, 0, stream>>>(Qb, Kb, Vtr, Qb);

        gemm_to<__hip_bfloat16, float, float><<<dim3(HIDDEN / BN, NTOK / BM), blk, 0, stream>>>(
            Qb, Wo, out, NTOK, HIDDEN, HIDDEN);
    }
}

// Round 7
// 1229.009 us; speedup vs baseline: 8.4726x; 1.2339x over previous
//
#include <hip/hip_runtime.h>
#include <hip/hip_bf16.h>
#include <math.h>

typedef __bf16  bf16x8 __attribute__((ext_vector_type(8)));
typedef __bf16  bf16x4 __attribute__((ext_vector_type(4)));
typedef __bf16  bf16x2 __attribute__((ext_vector_type(2)));
typedef float   f32x4  __attribute__((ext_vector_type(4)));
typedef unsigned int uint32;

#define HIDDEN 4096
#define NHQ    32
#define NHKV   8
#define HD     128
#define SEQ    2048
#define BATCH  2
#define NTOK   (BATCH * SEQ)
#define KVDIM  (NHKV * HD)   // 1024

#define MBYTE  (1024ull * 1024ull)

// ---------------------------------------------------------------------------
// Helpers
// ---------------------------------------------------------------------------
__device__ inline void load8(const float* p, __bf16* d)
{
    float4 a = *reinterpret_cast<const float4*>(p);
    float4 b = *reinterpret_cast<const float4*>(p + 4);
    d[0] = (__bf16)a.x; d[1] = (__bf16)a.y; d[2] = (__bf16)a.z; d[3] = (__bf16)a.w;
    d[4] = (__bf16)b.x; d[5] = (__bf16)b.y; d[6] = (__bf16)b.z; d[7] = (__bf16)b.w;
}
__device__ inline void load8(const __hip_bfloat16* p, __bf16* d)
{
    *reinterpret_cast<bf16x8*>(d) = *reinterpret_cast<const bf16x8*>(p);
}

__device__ inline void storeC(float* C, size_t idx, float v)          { C[idx] = v; }
__device__ inline void storeC(__hip_bfloat16* C, size_t idx, float v) { C[idx] = __float2bfloat16(v); }

// ---------------------------------------------------------------------------
// Elementwise cast fp32 -> bf16, 8 elems/thread.  (verified)
// ---------------------------------------------------------------------------
__global__ __launch_bounds__(256) void cast_f2b(
    const float* __restrict__ in, __hip_bfloat16* __restrict__ out, size_t n8)
{
    size_t i = (size_t)blockIdx.x * blockDim.x + threadIdx.x;
    if (i >= n8) return;
    const float* p = in + i * 8;
    float4 a = *reinterpret_cast<const float4*>(p);
    float4 b = *reinterpret_cast<const float4*>(p + 4);
    bf16x8 v;
    v[0] = (__bf16)a.x; v[1] = (__bf16)a.y; v[2] = (__bf16)a.z; v[3] = (__bf16)a.w;
    v[4] = (__bf16)b.x; v[5] = (__bf16)b.y; v[6] = (__bf16)b.z; v[7] = (__bf16)b.w;
    *reinterpret_cast<bf16x8*>(out + i * 8) = v;
}

// ---------------------------------------------------------------------------
// Transpose + cast: W fp32 [K][ldw] -> Wt bf16 [N][K]. 32x32 LDS tiles. (verified)
// ---------------------------------------------------------------------------
__global__ __launch_bounds__(256) void transpose_cast(
    const float* __restrict__ W, int ldw,
    __hip_bfloat16* __restrict__ Wt, int K)
{
    __shared__ __align__(16) float tf[32][36];
    const int k0 = blockIdx.x * 32;
    const int n0 = blockIdx.y * 32;
    const int r  = threadIdx.x >> 3;         // 0..31
    const int c4 = (threadIdx.x & 7) * 4;    // 0,4,...,28

    *reinterpret_cast<float4*>(&tf[r][c4]) =
        *reinterpret_cast<const float4*>(W + (size_t)(k0 + r) * ldw + n0 + c4);
    __syncthreads();

    bf16x4 o;
    o[0] = (__bf16)tf[c4 + 0][r]; o[1] = (__bf16)tf[c4 + 1][r];
    o[2] = (__bf16)tf[c4 + 2][r]; o[3] = (__bf16)tf[c4 + 3][r];
    *reinterpret_cast<bf16x4*>(Wt + (size_t)(n0 + r) * K + k0 + c4) = o;
}

// ---------------------------------------------------------------------------
// GEMM, reg-staged 128x128 tile: C = A @ Bt^T.  (verified round 5/6)
// ---------------------------------------------------------------------------
#define GBM 128
#define GBN 128
#define GBK 32

template <typename TC>
__global__ __launch_bounds__(256) void gemm128r(
    const __hip_bfloat16* __restrict__ A,
    const __hip_bfloat16* __restrict__ Bt,
    TC* __restrict__ C,
    int M, int N, int K, int ldc)
{
    __shared__ __align__(16) __bf16 As[GBM][GBK];   // 8 KB, linear
    __shared__ __align__(16) __bf16 Bs[GBN][GBK];   // 8 KB, linear

    const int tid  = threadIdx.x;
    const int w    = tid >> 6;
    const int lane = tid & 63;
    const int lrow = lane & 15;
    const int lq   = lane >> 4;
    const int bm   = blockIdx.y * GBM;
    const int bn   = blockIdx.x * GBN;
    const int wr   = (w >> 1) * 64;
    const int wc   = (w & 1) * 64;

    const int srow = tid >> 1;            // 0..127 (tile row)
    const int scol = (tid & 1) * 16;      // 0 or 16 (k offset)

    f32x4 acc[4][4] = {};

    const __hip_bfloat16* ga = A  + (size_t)(bm + srow) * K + scol;
    const __hip_bfloat16* gb = Bt + (size_t)(bn + srow) * K + scol;

    for (int k0 = 0; k0 < K; k0 += GBK) {
        bf16x8 a0 = *reinterpret_cast<const bf16x8*>(ga + k0);
        bf16x8 a1 = *reinterpret_cast<const bf16x8*>(ga + k0 + 8);
        bf16x8 b0 = *reinterpret_cast<const bf16x8*>(gb + k0);
        bf16x8 b1 = *reinterpret_cast<const bf16x8*>(gb + k0 + 8);

        *reinterpret_cast<bf16x8*>(&As[srow][scol])     = a0;
        *reinterpret_cast<bf16x8*>(&As[srow][scol + 8]) = a1;
        *reinterpret_cast<bf16x8*>(&Bs[srow][scol])     = b0;
        *reinterpret_cast<bf16x8*>(&Bs[srow][scol + 8]) = b1;

        __syncthreads();

        bf16x8 af[4], bfr[4];
        #pragma unroll
        for (int i = 0; i < 4; ++i) {
            af[i]  = *reinterpret_cast<const bf16x8*>(&As[wr + i * 16 + lrow][lq * 8]);
            bfr[i] = *reinterpret_cast<const bf16x8*>(&Bs[wc + i * 16 + lrow][lq * 8]);
        }
        #pragma unroll
        for (int mi = 0; mi < 4; ++mi)
            #pragma unroll
            for (int ni = 0; ni < 4; ++ni)
                acc[mi][ni] = __builtin_amdgcn_mfma_f32_16x16x32_bf16(
                    af[mi], bfr[ni], acc[mi][ni], 0, 0, 0);

        __syncthreads();
    }

    // Epilogue: D layout col=lane&15, row=(lane>>4)*4+reg
    #pragma unroll
    for (int mi = 0; mi < 4; ++mi)
        #pragma unroll
        for (int ni = 0; ni < 4; ++ni)
            #pragma unroll
            for (int r = 0; r < 4; ++r) {
                int row = bm + wr + mi * 16 + lq * 4 + r;
                int col = bn + wc + ni * 16 + lrow;
                storeC(C, (size_t)row * ldc + col, acc[mi][ni][r]);
            }
}

// ---------------------------------------------------------------------------
// Fallback GEMM (round-2 proven): C = A @ B, fp32/bf16 inputs staged to LDS.
// ---------------------------------------------------------------------------
#define BM 64
#define BN 64
#define BK 32
#define LDSS 40

template <typename TA, typename TB, typename TC>
__global__ __launch_bounds__(256) void gemm_to(
    const TA* __restrict__ A,
    const TB* __restrict__ B,
    TC* __restrict__ C,
    int M, int N, int K)
{
    __shared__ __align__(16) __bf16 As[BM][LDSS];
    __shared__ __align__(16) __bf16 Bs[BN][LDSS];

    const int tid  = threadIdx.x;
    const int bm   = blockIdx.y * BM;
    const int bn   = blockIdx.x * BN;
    const int wave = tid >> 6;
    const int lane = tid & 63;
    const int wr   = (wave >> 1) * 32;
    const int wc   = (wave & 1) * 32;
    const int lrow = lane & 15;
    const int lq   = lane >> 4;

    f32x4 acc[2][2] = {};

    const int ar = tid >> 2;
    const int ac = (tid & 3) * 8;
    const int br = tid >> 3;
    const int bc = (tid & 7) * 8;

    for (int k0 = 0; k0 < K; k0 += BK) {
        __bf16 abuf[8], bbuf[8];
        load8(A + (size_t)(bm + ar) * K + (k0 + ac), abuf);
        load8(B + (size_t)(k0 + br) * N + (bn + bc), bbuf);

        *reinterpret_cast<bf16x8*>(&As[ar][ac]) = *reinterpret_cast<bf16x8*>(abuf);
        #pragma unroll
        for (int j = 0; j < 8; ++j)
            Bs[bc + j][br] = bbuf[j];

        __syncthreads();

        bf16x8 afrag[2], bfrag[2];
        #pragma unroll
        for (int mi = 0; mi < 2; ++mi)
            afrag[mi] = *reinterpret_cast<const bf16x8*>(&As[wr + mi * 16 + lrow][lq * 8]);
        #pragma unroll
        for (int ni = 0; ni < 2; ++ni)
            bfrag[ni] = *reinterpret_cast<const bf16x8*>(&Bs[wc + ni * 16 + lrow][lq * 8]);

        #pragma unroll
        for (int mi = 0; mi < 2; ++mi)
            #pragma unroll
            for (int ni = 0; ni < 2; ++ni)
                acc[mi][ni] = __builtin_amdgcn_mfma_f32_16x16x32_bf16(
                    afrag[mi], bfrag[ni], acc[mi][ni], 0, 0, 0);

        __syncthreads();
    }

    #pragma unroll
    for (int mi = 0; mi < 2; ++mi)
        #pragma unroll
        for (int ni = 0; ni < 2; ++ni)
            #pragma unroll
            for (int r = 0; r < 4; ++r) {
                int row = bm + wr + mi * 16 + lq * 4 + r;
                int col = bn + wc + ni * 16 + lrow;
                storeC(C, (size_t)row * N + col, acc[mi][ni][r]);
            }
}

// ---------------------------------------------------------------------------
// RoPE in-place on bf16.  (verified)
// ---------------------------------------------------------------------------
__global__ __launch_bounds__(256) void rope_kernel(
    __hip_bfloat16* __restrict__ X, int nh, size_t total)
{
    size_t idx = (size_t)blockIdx.x * blockDim.x + threadIdx.x;
    if (idx >= total) return;
    int    i   = (int)(idx & 63);
    size_t t   = idx >> 6;
    int    h   = (int)(t % nh);
    size_t tok = t / nh;
    int    pos = (int)(tok & (SEQ - 1));

    float inv_freq = exp2f(-(float)i * (13.287712379549449f / 64.0f));
    float fr = (float)pos * inv_freq;
    float sv, cv;
    sincosf(fr, &sv, &cv);

    size_t base = tok * ((size_t)nh * HD) + (size_t)h * HD + i;
    float x1 = __bfloat162float(X[base]);
    float x2 = __bfloat162float(X[base + 64]);
    X[base]      = __float2bfloat16(x1 * cv - x2 * sv);
    X[base + 64] = __float2bfloat16(x2 * cv + x1 * sv);
}

// ---------------------------------------------------------------------------
// V transpose: Vb [b*SEQ + s][KVDIM] -> Vt [b*KVDIM + dg][SEQ]  (verified)
// ---------------------------------------------------------------------------
__global__ __launch_bounds__(256) void transpose_v(
    const __hip_bfloat16* __restrict__ Vb,
    __hip_bfloat16* __restrict__ Vt)
{
    __shared__ __align__(16) __bf16 t[32][36];
    const int bz = blockIdx.z;
    const int s0 = blockIdx.x * 32;
    const int c0 = blockIdx.y * 32;
    const int r  = threadIdx.x >> 3;
    const int c4 = (threadIdx.x & 7) * 4;

    *reinterpret_cast<bf16x4*>(&t[r][c4]) =
        *reinterpret_cast<const bf16x4*>(Vb + ((size_t)bz * SEQ + s0 + r) * KVDIM + c0 + c4);
    __syncthreads();

    bf16x4 o;
    o[0] = t[c4 + 0][r]; o[1] = t[c4 + 1][r];
    o[2] = t[c4 + 2][r]; o[3] = t[c4 + 3][r];
    *reinterpret_cast<bf16x4*>(Vt + ((size_t)bz * KVDIM + c0 + r) * SEQ + s0 + c4) = o;
}

// ---------------------------------------------------------------------------
// Flash attention with MFMA — 32 q-rows per wave, balanced tile mapping.
// Block = 4 waves = the 4 q-heads of one KV head; wave owns q-rows
// [q0, q0+32) as two 16-row halves sharing each K/V fetch (2x intensity).
// Balanced qt: consecutive dispatch pairs sum to const 63 -> even CU load.
// XCD-aware decode: bid%8 selects KV-head pair -> per-XCD L2 K/V locality.
// No barriers; LDS statically partitioned per wave.
// ---------------------------------------------------------------------------
__global__ __launch_bounds__(256) void attn_mfma(
    const __hip_bfloat16* __restrict__ Qg,   // [NTOK][HIDDEN]
    const __hip_bfloat16* __restrict__ Kg,   // [NTOK][KVDIM]
    const __hip_bfloat16* __restrict__ Vt,   // [B*KVDIM][SEQ]
    __hip_bfloat16* __restrict__ Og)         // [NTOK][HIDDEN] (may alias Qg)
{
    __shared__ __align__(16) __bf16 Pl[4][32][40];    // P rows for 32 q
    __shared__ __align__(16) __bf16 Ol[4][16][136];   // epilogue, reused per half

    const int wv   = threadIdx.x >> 6;
    const int lane = threadIdx.x & 63;
    const int lq   = lane & 15;   // q column (within a 16-row half)
    const int g    = lane >> 4;   // lane group

    const int bid = blockIdx.x;                      // [0, 1024)
    const int khb = (bid & 7) * 2 + ((bid >> 3) & 1);// [0,16): XCD-contig KV heads
    const int j   = bid >> 4;                        // [0,64)
    const int qt  = (j & 1) ? (j >> 1) : (63 - (j >> 1));  // balanced heavy/light
    const int b   = khb >> 3;
    const int kh  = khb & 7;
    const int qh  = kh * 4 + wv;
    const int q0  = qt * 32;

    // Q fragments for both halves (B-operand layout: row q0+h*16+lq, d=dj*32+g*8)
    bf16x8 qf[2][4];
#pragma unroll
    for (int h = 0; h < 2; ++h) {
        const __hip_bfloat16* qrow =
            Qg + ((size_t)b * SEQ + q0 + h * 16 + lq) * HIDDEN + (size_t)qh * HD;
#pragma unroll
        for (int dj = 0; dj < 4; ++dj)
            qf[h][dj] = *reinterpret_cast<const bf16x8*>(qrow + dj * 32 + g * 8);
    }

    const __hip_bfloat16* Kb = Kg + ((size_t)b * SEQ) * KVDIM + (size_t)kh * HD;
    const __hip_bfloat16* Vb = Vt + ((size_t)b * KVDIM + (size_t)kh * HD) * SEQ;

    f32x4 oacc0[8] = {};                 // half 0: O^T[d][q]
    f32x4 oacc1[8] = {};                 // half 1
    float m_run[2] = { -INFINITY, -INFINITY };
    float l_run[2] = { 0.0f, 0.0f };
    const float SCALE = 0.08838834764831845f;   // 1/sqrt(128)

    const int kv_len = q0 + 32;
    for (int k0 = 0; k0 < kv_len; k0 += 32) {
        // ---- K fragments for this tile
        bf16x8 kreg[8];
#pragma unroll
        for (int kt = 0; kt < 2; ++kt)
#pragma unroll
            for (int dj = 0; dj < 4; ++dj)
                kreg[kt * 4 + dj] = *reinterpret_cast<const bf16x8*>(
                    Kb + (size_t)(k0 + kt * 16 + lq) * KVDIM + dj * 32 + g * 8);

        // ---- S^T = K · Q^T, both q-halves (K amortized 2x)
        f32x4 sacc[2][2] = {};
        __builtin_amdgcn_s_setprio(1);
#pragma unroll
        for (int kt = 0; kt < 2; ++kt)
#pragma unroll
            for (int dj = 0; dj < 4; ++dj) {
                sacc[0][kt] = __builtin_amdgcn_mfma_f32_16x16x32_bf16(
                    kreg[kt * 4 + dj], qf[0][dj], sacc[0][kt], 0, 0, 0);
                sacc[1][kt] = __builtin_amdgcn_mfma_f32_16x16x32_bf16(
                    kreg[kt * 4 + dj], qf[1][dj], sacc[1][kt], 0, 0, 0);
            }
        __builtin_amdgcn_s_setprio(0);

        // ---- V fragments (issue now; latency hides under softmax)
        bf16x8 vreg[8];
#pragma unroll
        for (int dt = 0; dt < 8; ++dt)
            vreg[dt] = *reinterpret_cast<const bf16x8*>(
                Vb + (size_t)(dt * 16 + lq) * SEQ + k0 + 8 * g);

        // ---- online softmax per half
        float corr[2];
#pragma unroll
        for (int h = 0; h < 2; ++h) {
            const int q_g = q0 + h * 16 + lq;
            float p[2][4];
            float tmax = -INFINITY;
#pragma unroll
            for (int kt = 0; kt < 2; ++kt)
#pragma unroll
                for (int r = 0; r < 4; ++r) {
                    int   k_g = k0 + kt * 16 + 4 * g + r;
                    float s   = sacc[h][kt][r] * SCALE;
                    s = (k_g <= q_g) ? s : -INFINITY;
                    p[kt][r] = s;
                    tmax = fmaxf(tmax, s);
                }
            tmax = fmaxf(tmax, __shfl_xor(tmax, 16));
            tmax = fmaxf(tmax, __shfl_xor(tmax, 32));

            float m_new = fmaxf(m_run[h], tmax);
            corr[h] = __expf(m_run[h] - m_new);      // 0 on first tile
            float tsum = 0.0f;
#pragma unroll
            for (int kt = 0; kt < 2; ++kt)
#pragma unroll
                for (int r = 0; r < 4; ++r) {
                    float e = __expf(p[kt][r] - m_new);   // masked -> 0
                    p[kt][r] = e;
                    tsum += e;
                }

            // P -> bf16 LDS (write, then reduce while ds_write completes)
#pragma unroll
            for (int kt = 0; kt < 2; ++kt) {
                bf16x2 lo, hi;
                lo[0] = (__bf16)p[kt][0]; lo[1] = (__bf16)p[kt][1];
                hi[0] = (__bf16)p[kt][2]; hi[1] = (__bf16)p[kt][3];
                *reinterpret_cast<bf16x2*>(&Pl[wv][h * 16 + lq][kt * 16 + 4 * g])     = lo;
                *reinterpret_cast<bf16x2*>(&Pl[wv][h * 16 + lq][kt * 16 + 4 * g + 2]) = hi;
            }

            tsum += __shfl_xor(tsum, 16);
            tsum += __shfl_xor(tsum, 32);
            l_run[h] = l_run[h] * corr[h] + tsum;
            m_run[h] = m_new;
        }

        bf16x8 pf0 = *reinterpret_cast<const bf16x8*>(&Pl[wv][lq][8 * g]);
        bf16x8 pf1 = *reinterpret_cast<const bf16x8*>(&Pl[wv][16 + lq][8 * g]);

        // ---- rescale accumulators, then O^T += V^T · P^T (V amortized 2x)
#pragma unroll
        for (int dt = 0; dt < 8; ++dt) {
            oacc0[dt][0] *= corr[0]; oacc0[dt][1] *= corr[0];
            oacc0[dt][2] *= corr[0]; oacc0[dt][3] *= corr[0];
            oacc1[dt][0] *= corr[1]; oacc1[dt][1] *= corr[1];
            oacc1[dt][2] *= corr[1]; oacc1[dt][3] *= corr[1];
        }
        __builtin_amdgcn_s_setprio(1);
#pragma unroll
        for (int dt = 0; dt < 8; ++dt) {
            oacc0[dt] = __builtin_amdgcn_mfma_f32_16x16x32_bf16(vreg[dt], pf0, oacc0[dt], 0, 0, 0);
            oacc1[dt] = __builtin_amdgcn_mfma_f32_16x16x32_bf16(vreg[dt], pf1, oacc1[dt], 0, 0, 0);
        }
        __builtin_amdgcn_s_setprio(0);
    }

    // ---- epilogue per half: normalize, LDS transpose, coalesced store.
    // Same-wave Ol reuse between halves is ordered by lgkmcnt (program order).
#pragma unroll
    for (int h = 0; h < 2; ++h) {
        const f32x4* oa = h ? oacc1 : oacc0;
        float inv = 1.0f / l_run[h];
#pragma unroll
        for (int dt = 0; dt < 8; ++dt) {
            bf16x2 lo, hi;
            lo[0] = (__bf16)(oa[dt][0] * inv); lo[1] = (__bf16)(oa[dt][1] * inv);
            hi[0] = (__bf16)(oa[dt][2] * inv); hi[1] = (__bf16)(oa[dt][3] * inv);
            *reinterpret_cast<bf16x2*>(&Ol[wv][lq][dt * 16 + 4 * g])     = lo;
            *reinterpret_cast<bf16x2*>(&Ol[wv][lq][dt * 16 + 4 * g + 2]) = hi;
        }

        __hip_bfloat16* orow =
            Og + ((size_t)b * SEQ + q0 + h * 16 + lq) * HIDDEN + (size_t)qh * HD;
#pragma unroll
        for (int jj = 0; jj < 4; ++jj) {
            int c = jj * 4 + g;
            bf16x8 v = *reinterpret_cast<const bf16x8*>(&Ol[wv][lq][c * 8]);
            *reinterpret_cast<bf16x8*>(orow + c * 8) = v;
        }
    }
}

// ---------------------------------------------------------------------------
// Orchestration. Two paths:
//  FAST (ws_size >= 112 MB): all scratch in ws, d_out written once (fp32 out).
//    ws: Qb[0:32M] Kb[32:40M] Vb[40:48M] xb[48:80M] Wt[80:112M]
//        Vt[48:56M] overlays xb after xb is dead (post V-GEMM).
//  FALLBACK (else): round-2 proven path (fp32-input gemm_to).
// ---------------------------------------------------------------------------
extern "C" void kernel_launch(void* const* d_in, const int* in_sizes, int n_in,
                              void* d_out, int out_size, void* d_ws, size_t ws_size,
                              hipStream_t stream)
{
    const float* x  = (const float*)d_in[0];
    const float* Wq = (const float*)d_in[1];
    const float* Wk = (const float*)d_in[2];
    const float* Wv = (const float*)d_in[3];
    const float* Wo = (const float*)d_in[4];
    float* out = (float*)d_out;

    char* ws = (char*)d_ws;
    dim3 blk(256);

    if (ws_size >= 112 * MBYTE) {
        // ---------------- FAST PATH: scratch entirely in workspace ----------
        __hip_bfloat16* Qb = (__hip_bfloat16*)(ws +  0 * MBYTE);
        __hip_bfloat16* Kb = (__hip_bfloat16*)(ws + 32 * MBYTE);
        __hip_bfloat16* Vb = (__hip_bfloat16*)(ws + 40 * MBYTE);
        __hip_bfloat16* xb = (__hip_bfloat16*)(ws + 48 * MBYTE);
        __hip_bfloat16* Vt = (__hip_bfloat16*)(ws + 48 * MBYTE);   // overlays dead xb
        __hip_bfloat16* Wt = (__hip_bfloat16*)(ws + 80 * MBYTE);

        cast_f2b<<<(NTOK * HIDDEN / 8 + 255) / 256, blk, 0, stream>>>(
            x, xb, (size_t)NTOK * HIDDEN / 8);

        // Q = xb @ Wq
        transpose_cast<<<dim3(HIDDEN / 32, HIDDEN / 32), blk, 0, stream>>>(Wq, HIDDEN, Wt, HIDDEN);
        gemm128r<__hip_bfloat16><<<dim3(HIDDEN / GBN, NTOK / GBM), blk, 0, stream>>>(
            xb, Wt, Qb, NTOK, HIDDEN, HIDDEN, HIDDEN);

        // K = xb @ Wk
        transpose_cast<<<dim3(HIDDEN / 32, KVDIM / 32), blk, 0, stream>>>(Wk, KVDIM, Wt, HIDDEN);
        gemm128r<__hip_bfloat16><<<dim3(KVDIM / GBN, NTOK / GBM), blk, 0, stream>>>(
            xb, Wt, Kb, NTOK, KVDIM, HIDDEN, KVDIM);

        // V = xb @ Wv  (last consumer of xb)
        transpose_cast<<<dim3(HIDDEN / 32, KVDIM / 32), blk, 0, stream>>>(Wv, KVDIM, Wt, HIDDEN);
        gemm128r<__hip_bfloat16><<<dim3(KVDIM / GBN, NTOK / GBM), blk, 0, stream>>>(
            xb, Wt, Vb, NTOK, KVDIM, HIDDEN, KVDIM);

        // RoPE in place
        {
            size_t totq = (size_t)NTOK * NHQ * 64;
            size_t totk = (size_t)NTOK * NHKV * 64;
            rope_kernel<<<(unsigned)((totq + 255) / 256), blk, 0, stream>>>(Qb, NHQ,  totq);
            rope_kernel<<<(unsigned)((totk + 255) / 256), blk, 0, stream>>>(Kb, NHKV, totk);
        }

        // V^T over dead xb region
        transpose_v<<<dim3(SEQ / 32, KVDIM / 32, BATCH), blk, 0, stream>>>(Vb, Vt);

        // 32 q-rows per wave: BATCH*NHKV*(SEQ/32) = 1024 blocks
        attn_mfma<<<BATCH * NHKV * (SEQ / 32), blk, 0, stream>>>(Qb, Kb, Vt, Qb);

        // out = O @ Wo (full Wo^T fits in Wt region)
        transpose_cast<<<dim3(HIDDEN / 32, HIDDEN / 32), blk, 0, stream>>>(Wo, HIDDEN, Wt, HIDDEN);
        gemm128r<float><<<dim3(HIDDEN / GBN, NTOK / GBM), blk, 0, stream>>>(
            Qb, Wt, out, NTOK, HIDDEN, HIDDEN, HIDDEN);
    } else {
        // ---------------- FALLBACK: round-2 proven path ---------------------
        __hip_bfloat16* Qb = (__hip_bfloat16*)ws;
        __hip_bfloat16* Kb = (__hip_bfloat16*)(ws + (size_t)NTOK * HIDDEN * 2);
        __hip_bfloat16* Vb = (__hip_bfloat16*)(ws + (size_t)NTOK * HIDDEN * 2
                                                  + (size_t)NTOK * KVDIM * 2);

        const size_t base_ws  = (size_t)NTOK * HIDDEN * 2 + 2 * (size_t)NTOK * KVDIM * 2;
        const size_t vt_bytes = (size_t)NTOK * KVDIM * 2;
        __hip_bfloat16* Vtr = (ws_size >= base_ws + vt_bytes)
                            ? (__hip_bfloat16*)(ws + base_ws)
                            : (__hip_bfloat16*)d_out;

        gemm_to<float, float, __hip_bfloat16><<<dim3(HIDDEN / BN, NTOK / BM), blk, 0, stream>>>(
            x, Wq, Qb, NTOK, HIDDEN, HIDDEN);
        gemm_to<float, float, __hip_bfloat16><<<dim3(KVDIM / BN, NTOK / BM), blk, 0, stream>>>(
            x, Wk, Kb, NTOK, KVDIM, HIDDEN);
        gemm_to<float, float, __hip_bfloat16><<<dim3(KVDIM / BN, NTOK / BM), blk, 0, stream>>>(
            x, Wv, Vb, NTOK, KVDIM, HIDDEN);

        {
            size_t totq = (size_t)NTOK * NHQ * 64;
            size_t totk = (size_t)NTOK * NHKV * 64;
            rope_kernel<<<(unsigned)((totq + 255) / 256), blk, 0, stream>>>(Qb, NHQ,  totq);
            rope_kernel<<<(unsigned)((totk + 255) / 256), blk, 0, stream>>>(Kb, NHKV, totk);
        }

        transpose_v<<<dim3(SEQ / 32, KVDIM / 32, BATCH), blk, 0, stream>>>(Vb, Vtr);

        attn_mfma<<<BATCH * NHKV * (SEQ / 32), blk, 0, stream>>>(Qb, Kb, Vtr, Qb);

        gemm_to<__hip_bfloat16, float, float><<<dim3(HIDDEN / BN, NTOK / BM), blk, 0, stream>>>(
            Qb, Wo, out, NTOK, HIDDEN, HIDDEN);
    }
}

// Round 8
// 1061.034 us; speedup vs baseline: 9.8139x; 1.1583x over previous
//
#include <hip/hip_runtime.h>
#include <hip/hip_bf16.h>
#include <math.h>

typedef __bf16  bf16x8 __attribute__((ext_vector_type(8)));
typedef __bf16  bf16x4 __attribute__((ext_vector_type(4)));
typedef __bf16  bf16x2 __attribute__((ext_vector_type(2)));
typedef float   f32x4  __attribute__((ext_vector_type(4)));
typedef unsigned int uint32;

#define HIDDEN 4096
#define NHQ    32
#define NHKV   8
#define HD     128
#define SEQ    2048
#define BATCH  2
#define NTOK   (BATCH * SEQ)
#define KVDIM  (NHKV * HD)   // 1024

#define MBYTE  (1024ull * 1024ull)

// ---------------------------------------------------------------------------
// Helpers
// ---------------------------------------------------------------------------
__device__ inline void load8(const float* p, __bf16* d)
{
    float4 a = *reinterpret_cast<const float4*>(p);
    float4 b = *reinterpret_cast<const float4*>(p + 4);
    d[0] = (__bf16)a.x; d[1] = (__bf16)a.y; d[2] = (__bf16)a.z; d[3] = (__bf16)a.w;
    d[4] = (__bf16)b.x; d[5] = (__bf16)b.y; d[6] = (__bf16)b.z; d[7] = (__bf16)b.w;
}
__device__ inline void load8(const __hip_bfloat16* p, __bf16* d)
{
    *reinterpret_cast<bf16x8*>(d) = *reinterpret_cast<const bf16x8*>(p);
}

__device__ inline void storeC(float* C, size_t idx, float v)          { C[idx] = v; }
__device__ inline void storeC(__hip_bfloat16* C, size_t idx, float v) { C[idx] = __float2bfloat16(v); }

// ---------------------------------------------------------------------------
// Elementwise cast fp32 -> bf16, 8 elems/thread.  (verified)
// ---------------------------------------------------------------------------
__global__ __launch_bounds__(256) void cast_f2b(
    const float* __restrict__ in, __hip_bfloat16* __restrict__ out, size_t n8)
{
    size_t i = (size_t)blockIdx.x * blockDim.x + threadIdx.x;
    if (i >= n8) return;
    const float* p = in + i * 8;
    float4 a = *reinterpret_cast<const float4*>(p);
    float4 b = *reinterpret_cast<const float4*>(p + 4);
    bf16x8 v;
    v[0] = (__bf16)a.x; v[1] = (__bf16)a.y; v[2] = (__bf16)a.z; v[3] = (__bf16)a.w;
    v[4] = (__bf16)b.x; v[5] = (__bf16)b.y; v[6] = (__bf16)b.z; v[7] = (__bf16)b.w;
    *reinterpret_cast<bf16x8*>(out + i * 8) = v;
}

// ---------------------------------------------------------------------------
// Transpose + cast: W fp32 [K][ldw] -> Wt bf16 [N][K]. 32x32 LDS tiles. (verified)
// ---------------------------------------------------------------------------
__global__ __launch_bounds__(256) void transpose_cast(
    const float* __restrict__ W, int ldw,
    __hip_bfloat16* __restrict__ Wt, int K)
{
    __shared__ __align__(16) float tf[32][36];
    const int k0 = blockIdx.x * 32;
    const int n0 = blockIdx.y * 32;
    const int r  = threadIdx.x >> 3;         // 0..31
    const int c4 = (threadIdx.x & 7) * 4;    // 0,4,...,28

    *reinterpret_cast<float4*>(&tf[r][c4]) =
        *reinterpret_cast<const float4*>(W + (size_t)(k0 + r) * ldw + n0 + c4);
    __syncthreads();

    bf16x4 o;
    o[0] = (__bf16)tf[c4 + 0][r]; o[1] = (__bf16)tf[c4 + 1][r];
    o[2] = (__bf16)tf[c4 + 2][r]; o[3] = (__bf16)tf[c4 + 3][r];
    *reinterpret_cast<bf16x4*>(Wt + (size_t)(n0 + r) * K + k0 + c4) = o;
}

// ---------------------------------------------------------------------------
// GEMM, reg-staged 128x128 tile with register prefetch pipeline:
// C = A @ Bt^T. A bf16 [M][K], Bt bf16 [N][K]. BK=32, 4 waves, wave = 64x64.
// Per K-step: ds_write prefetched regs -> barrier -> ISSUE NEXT TILE's global
// loads (latency hides under ds_read+MFMA) -> ds_read frags -> 16 MFMA -> barrier.
// ---------------------------------------------------------------------------
#define GBM 128
#define GBN 128
#define GBK 32

template <typename TC>
__global__ __launch_bounds__(256) void gemm128r(
    const __hip_bfloat16* __restrict__ A,
    const __hip_bfloat16* __restrict__ Bt,
    TC* __restrict__ C,
    int M, int N, int K, int ldc)
{
    __shared__ __align__(16) __bf16 As[GBM][GBK];   // 8 KB, linear
    __shared__ __align__(16) __bf16 Bs[GBN][GBK];   // 8 KB, linear

    const int tid  = threadIdx.x;
    const int w    = tid >> 6;
    const int lane = tid & 63;
    const int lrow = lane & 15;
    const int lq   = lane >> 4;
    const int bm   = blockIdx.y * GBM;
    const int bn   = blockIdx.x * GBN;
    const int wr   = (w >> 1) * 64;
    const int wc   = (w & 1) * 64;

    const int srow = tid >> 1;            // 0..127 (tile row)
    const int scol = (tid & 1) * 16;      // 0 or 16 (k offset)

    f32x4 acc[4][4] = {};

    const __hip_bfloat16* ga = A  + (size_t)(bm + srow) * K + scol;
    const __hip_bfloat16* gb = Bt + (size_t)(bn + srow) * K + scol;

    // Prologue: tile 0 into registers.
    bf16x8 pa0 = *reinterpret_cast<const bf16x8*>(ga);
    bf16x8 pa1 = *reinterpret_cast<const bf16x8*>(ga + 8);
    bf16x8 pb0 = *reinterpret_cast<const bf16x8*>(gb);
    bf16x8 pb1 = *reinterpret_cast<const bf16x8*>(gb + 8);

    for (int k0 = 0; k0 < K; k0 += GBK) {
        *reinterpret_cast<bf16x8*>(&As[srow][scol])     = pa0;
        *reinterpret_cast<bf16x8*>(&As[srow][scol + 8]) = pa1;
        *reinterpret_cast<bf16x8*>(&Bs[srow][scol])     = pb0;
        *reinterpret_cast<bf16x8*>(&Bs[srow][scol + 8]) = pb1;

        __syncthreads();

        // Prefetch next tile (uniform branch): latency hides under MFMA below.
        if (k0 + GBK < K) {
            pa0 = *reinterpret_cast<const bf16x8*>(ga + k0 + GBK);
            pa1 = *reinterpret_cast<const bf16x8*>(ga + k0 + GBK + 8);
            pb0 = *reinterpret_cast<const bf16x8*>(gb + k0 + GBK);
            pb1 = *reinterpret_cast<const bf16x8*>(gb + k0 + GBK + 8);
        }

        bf16x8 af[4], bfr[4];
        #pragma unroll
        for (int i = 0; i < 4; ++i) {
            af[i]  = *reinterpret_cast<const bf16x8*>(&As[wr + i * 16 + lrow][lq * 8]);
            bfr[i] = *reinterpret_cast<const bf16x8*>(&Bs[wc + i * 16 + lrow][lq * 8]);
        }
        #pragma unroll
        for (int mi = 0; mi < 4; ++mi)
            #pragma unroll
            for (int ni = 0; ni < 4; ++ni)
                acc[mi][ni] = __builtin_amdgcn_mfma_f32_16x16x32_bf16(
                    af[mi], bfr[ni], acc[mi][ni], 0, 0, 0);

        __syncthreads();
    }

    // Epilogue: D layout col=lane&15, row=(lane>>4)*4+reg
    #pragma unroll
    for (int mi = 0; mi < 4; ++mi)
        #pragma unroll
        for (int ni = 0; ni < 4; ++ni)
            #pragma unroll
            for (int r = 0; r < 4; ++r) {
                int row = bm + wr + mi * 16 + lq * 4 + r;
                int col = bn + wc + ni * 16 + lrow;
                storeC(C, (size_t)row * ldc + col, acc[mi][ni][r]);
            }
}

// ---------------------------------------------------------------------------
// Fallback GEMM (round-2 proven): C = A @ B, fp32/bf16 inputs staged to LDS.
// ---------------------------------------------------------------------------
#define BM 64
#define BN 64
#define BK 32
#define LDSS 40

template <typename TA, typename TB, typename TC>
__global__ __launch_bounds__(256) void gemm_to(
    const TA* __restrict__ A,
    const TB* __restrict__ B,
    TC* __restrict__ C,
    int M, int N, int K)
{
    __shared__ __align__(16) __bf16 As[BM][LDSS];
    __shared__ __align__(16) __bf16 Bs[BN][LDSS];

    const int tid  = threadIdx.x;
    const int bm   = blockIdx.y * BM;
    const int bn   = blockIdx.x * BN;
    const int wave = tid >> 6;
    const int lane = tid & 63;
    const int wr   = (wave >> 1) * 32;
    const int wc   = (wave & 1) * 32;
    const int lrow = lane & 15;
    const int lq   = lane >> 4;

    f32x4 acc[2][2] = {};

    const int ar = tid >> 2;
    const int ac = (tid & 3) * 8;
    const int br = tid >> 3;
    const int bc = (tid & 7) * 8;

    for (int k0 = 0; k0 < K; k0 += BK) {
        __bf16 abuf[8], bbuf[8];
        load8(A + (size_t)(bm + ar) * K + (k0 + ac), abuf);
        load8(B + (size_t)(k0 + br) * N + (bn + bc), bbuf);

        *reinterpret_cast<bf16x8*>(&As[ar][ac]) = *reinterpret_cast<bf16x8*>(abuf);
        #pragma unroll
        for (int j = 0; j < 8; ++j)
            Bs[bc + j][br] = bbuf[j];

        __syncthreads();

        bf16x8 afrag[2], bfrag[2];
        #pragma unroll
        for (int mi = 0; mi < 2; ++mi)
            afrag[mi] = *reinterpret_cast<const bf16x8*>(&As[wr + mi * 16 + lrow][lq * 8]);
        #pragma unroll
        for (int ni = 0; ni < 2; ++ni)
            bfrag[ni] = *reinterpret_cast<const bf16x8*>(&Bs[wc + ni * 16 + lrow][lq * 8]);

        #pragma unroll
        for (int mi = 0; mi < 2; ++mi)
            #pragma unroll
            for (int ni = 0; ni < 2; ++ni)
                acc[mi][ni] = __builtin_amdgcn_mfma_f32_16x16x32_bf16(
                    afrag[mi], bfrag[ni], acc[mi][ni], 0, 0, 0);

        __syncthreads();
    }

    #pragma unroll
    for (int mi = 0; mi < 2; ++mi)
        #pragma unroll
        for (int ni = 0; ni < 2; ++ni)
            #pragma unroll
            for (int r = 0; r < 4; ++r) {
                int row = bm + wr + mi * 16 + lq * 4 + r;
                int col = bn + wc + ni * 16 + lrow;
                storeC(C, (size_t)row * N + col, acc[mi][ni][r]);
            }
}

// ---------------------------------------------------------------------------
// RoPE in-place on bf16.  (verified)
// ---------------------------------------------------------------------------
__global__ __launch_bounds__(256) void rope_kernel(
    __hip_bfloat16* __restrict__ X, int nh, size_t total)
{
    size_t idx = (size_t)blockIdx.x * blockDim.x + threadIdx.x;
    if (idx >= total) return;
    int    i   = (int)(idx & 63);
    size_t t   = idx >> 6;
    int    h   = (int)(t % nh);
    size_t tok = t / nh;
    int    pos = (int)(tok & (SEQ - 1));

    float inv_freq = exp2f(-(float)i * (13.287712379549449f / 64.0f));
    float fr = (float)pos * inv_freq;
    float sv, cv;
    sincosf(fr, &sv, &cv);

    size_t base = tok * ((size_t)nh * HD) + (size_t)h * HD + i;
    float x1 = __bfloat162float(X[base]);
    float x2 = __bfloat162float(X[base + 64]);
    X[base]      = __float2bfloat16(x1 * cv - x2 * sv);
    X[base + 64] = __float2bfloat16(x2 * cv + x1 * sv);
}

// ---------------------------------------------------------------------------
// V transpose: Vb [b*SEQ + s][KVDIM] -> Vt [b*KVDIM + dg][SEQ]  (verified)
// ---------------------------------------------------------------------------
__global__ __launch_bounds__(256) void transpose_v(
    const __hip_bfloat16* __restrict__ Vb,
    __hip_bfloat16* __restrict__ Vt)
{
    __shared__ __align__(16) __bf16 t[32][36];
    const int bz = blockIdx.z;
    const int s0 = blockIdx.x * 32;
    const int c0 = blockIdx.y * 32;
    const int r  = threadIdx.x >> 3;
    const int c4 = (threadIdx.x & 7) * 4;

    *reinterpret_cast<bf16x4*>(&t[r][c4]) =
        *reinterpret_cast<const bf16x4*>(Vb + ((size_t)bz * SEQ + s0 + r) * KVDIM + c0 + c4);
    __syncthreads();

    bf16x4 o;
    o[0] = t[c4 + 0][r]; o[1] = t[c4 + 1][r];
    o[2] = t[c4 + 2][r]; o[3] = t[c4 + 3][r];
    *reinterpret_cast<bf16x4*>(Vt + ((size_t)bz * KVDIM + c0 + r) * SEQ + s0 + c4) = o;
}

// ---------------------------------------------------------------------------
// Flash attention with MFMA — 32 q-rows per WAVE-SIZED BLOCK (64 threads).
// 4096 independent blocks: finest scheduling granularity, best CU packing.
// Wave owns q-rows [q0, q0+32) as two 16-row halves sharing each K/V fetch.
// Balanced qt: consecutive j pairs sum to const 63 -> even CU load.
// XCD-aware decode: bid&7 -> KV-head pair per XCD L2.
// ---------------------------------------------------------------------------
__global__ __launch_bounds__(64) void attn_mfma(
    const __hip_bfloat16* __restrict__ Qg,   // [NTOK][HIDDEN]
    const __hip_bfloat16* __restrict__ Kg,   // [NTOK][KVDIM]
    const __hip_bfloat16* __restrict__ Vt,   // [B*KVDIM][SEQ]
    __hip_bfloat16* __restrict__ Og)         // [NTOK][HIDDEN] (may alias Qg)
{
    __shared__ __align__(16) __bf16 Pl[32][40];    // P rows for 32 q
    __shared__ __align__(16) __bf16 Ol[16][136];   // epilogue, reused per half

    const int lane = threadIdx.x;   // 0..63
    const int lq   = lane & 15;     // q column (within a 16-row half)
    const int g    = lane >> 4;     // lane group

    const int bid = blockIdx.x;                      // [0, 4096)
    const int khb = (bid & 7) * 2 + ((bid >> 3) & 1);// [0,16): XCD-contig KV heads
    const int wv  = (bid >> 4) & 3;                  // q-head within group
    const int j   = bid >> 6;                        // [0,64)
    const int qt  = (j & 1) ? (j >> 1) : (63 - (j >> 1));  // balanced heavy/light
    const int b   = khb >> 3;
    const int kh  = khb & 7;
    const int qh  = kh * 4 + wv;
    const int q0  = qt * 32;

    // Q fragments for both halves (B-operand layout: row q0+h*16+lq, d=dj*32+g*8)
    bf16x8 qf[2][4];
#pragma unroll
    for (int h = 0; h < 2; ++h) {
        const __hip_bfloat16* qrow =
            Qg + ((size_t)b * SEQ + q0 + h * 16 + lq) * HIDDEN + (size_t)qh * HD;
#pragma unroll
        for (int dj = 0; dj < 4; ++dj)
            qf[h][dj] = *reinterpret_cast<const bf16x8*>(qrow + dj * 32 + g * 8);
    }

    const __hip_bfloat16* Kb = Kg + ((size_t)b * SEQ) * KVDIM + (size_t)kh * HD;
    const __hip_bfloat16* Vb = Vt + ((size_t)b * KVDIM + (size_t)kh * HD) * SEQ;

    f32x4 oacc0[8] = {};                 // half 0: O^T[d][q]
    f32x4 oacc1[8] = {};                 // half 1
    float m_run[2] = { -INFINITY, -INFINITY };
    float l_run[2] = { 0.0f, 0.0f };
    const float SCALE = 0.08838834764831845f;   // 1/sqrt(128)

    const int kv_len = q0 + 32;
    for (int k0 = 0; k0 < kv_len; k0 += 32) {
        // ---- K fragments for this tile
        bf16x8 kreg[8];
#pragma unroll
        for (int kt = 0; kt < 2; ++kt)
#pragma unroll
            for (int dj = 0; dj < 4; ++dj)
                kreg[kt * 4 + dj] = *reinterpret_cast<const bf16x8*>(
                    Kb + (size_t)(k0 + kt * 16 + lq) * KVDIM + dj * 32 + g * 8);

        // ---- S^T = K · Q^T, both q-halves (K amortized 2x)
        f32x4 sacc[2][2] = {};
        __builtin_amdgcn_s_setprio(1);
#pragma unroll
        for (int kt = 0; kt < 2; ++kt)
#pragma unroll
            for (int dj = 0; dj < 4; ++dj) {
                sacc[0][kt] = __builtin_amdgcn_mfma_f32_16x16x32_bf16(
                    kreg[kt * 4 + dj], qf[0][dj], sacc[0][kt], 0, 0, 0);
                sacc[1][kt] = __builtin_amdgcn_mfma_f32_16x16x32_bf16(
                    kreg[kt * 4 + dj], qf[1][dj], sacc[1][kt], 0, 0, 0);
            }
        __builtin_amdgcn_s_setprio(0);

        // ---- V fragments (issue now; latency hides under softmax)
        bf16x8 vreg[8];
#pragma unroll
        for (int dt = 0; dt < 8; ++dt)
            vreg[dt] = *reinterpret_cast<const bf16x8*>(
                Vb + (size_t)(dt * 16 + lq) * SEQ + k0 + 8 * g);

        // ---- online softmax per half
        float corr[2];
#pragma unroll
        for (int h = 0; h < 2; ++h) {
            const int q_g = q0 + h * 16 + lq;
            float p[2][4];
            float tmax = -INFINITY;
#pragma unroll
            for (int kt = 0; kt < 2; ++kt)
#pragma unroll
                for (int r = 0; r < 4; ++r) {
                    int   k_g = k0 + kt * 16 + 4 * g + r;
                    float s   = sacc[h][kt][r] * SCALE;
                    s = (k_g <= q_g) ? s : -INFINITY;
                    p[kt][r] = s;
                    tmax = fmaxf(tmax, s);
                }
            tmax = fmaxf(tmax, __shfl_xor(tmax, 16));
            tmax = fmaxf(tmax, __shfl_xor(tmax, 32));

            float m_new = fmaxf(m_run[h], tmax);
            corr[h] = __expf(m_run[h] - m_new);      // 0 on first tile
            float tsum = 0.0f;
#pragma unroll
            for (int kt = 0; kt < 2; ++kt)
#pragma unroll
                for (int r = 0; r < 4; ++r) {
                    float e = __expf(p[kt][r] - m_new);   // masked -> 0
                    p[kt][r] = e;
                    tsum += e;
                }

            // P -> bf16 LDS (write, then reduce while ds_write completes)
#pragma unroll
            for (int kt = 0; kt < 2; ++kt) {
                bf16x2 lo, hi;
                lo[0] = (__bf16)p[kt][0]; lo[1] = (__bf16)p[kt][1];
                hi[0] = (__bf16)p[kt][2]; hi[1] = (__bf16)p[kt][3];
                *reinterpret_cast<bf16x2*>(&Pl[h * 16 + lq][kt * 16 + 4 * g])     = lo;
                *reinterpret_cast<bf16x2*>(&Pl[h * 16 + lq][kt * 16 + 4 * g + 2]) = hi;
            }

            tsum += __shfl_xor(tsum, 16);
            tsum += __shfl_xor(tsum, 32);
            l_run[h] = l_run[h] * corr[h] + tsum;
            m_run[h] = m_new;
        }

        bf16x8 pf0 = *reinterpret_cast<const bf16x8*>(&Pl[lq][8 * g]);
        bf16x8 pf1 = *reinterpret_cast<const bf16x8*>(&Pl[16 + lq][8 * g]);

        // ---- rescale accumulators, then O^T += V^T · P^T (V amortized 2x)
#pragma unroll
        for (int dt = 0; dt < 8; ++dt) {
            oacc0[dt][0] *= corr[0]; oacc0[dt][1] *= corr[0];
            oacc0[dt][2] *= corr[0]; oacc0[dt][3] *= corr[0];
            oacc1[dt][0] *= corr[1]; oacc1[dt][1] *= corr[1];
            oacc1[dt][2] *= corr[1]; oacc1[dt][3] *= corr[1];
        }
        __builtin_amdgcn_s_setprio(1);
#pragma unroll
        for (int dt = 0; dt < 8; ++dt) {
            oacc0[dt] = __builtin_amdgcn_mfma_f32_16x16x32_bf16(vreg[dt], pf0, oacc0[dt], 0, 0, 0);
            oacc1[dt] = __builtin_amdgcn_mfma_f32_16x16x32_bf16(vreg[dt], pf1, oacc1[dt], 0, 0, 0);
        }
        __builtin_amdgcn_s_setprio(0);
    }

    // ---- epilogue per half: normalize, LDS transpose, coalesced store.
    // Same-wave Ol reuse between halves is ordered by lgkmcnt (program order).
#pragma unroll
    for (int h = 0; h < 2; ++h) {
        const f32x4* oa = h ? oacc1 : oacc0;
        float inv = 1.0f / l_run[h];
#pragma unroll
        for (int dt = 0; dt < 8; ++dt) {
            bf16x2 lo, hi;
            lo[0] = (__bf16)(oa[dt][0] * inv); lo[1] = (__bf16)(oa[dt][1] * inv);
            hi[0] = (__bf16)(oa[dt][2] * inv); hi[1] = (__bf16)(oa[dt][3] * inv);
            *reinterpret_cast<bf16x2*>(&Ol[lq][dt * 16 + 4 * g])     = lo;
            *reinterpret_cast<bf16x2*>(&Ol[lq][dt * 16 + 4 * g + 2]) = hi;
        }

        __hip_bfloat16* orow =
            Og + ((size_t)b * SEQ + q0 + h * 16 + lq) * HIDDEN + (size_t)qh * HD;
#pragma unroll
        for (int jj = 0; jj < 4; ++jj) {
            int c = jj * 4 + g;
            bf16x8 v = *reinterpret_cast<const bf16x8*>(&Ol[lq][c * 8]);
            *reinterpret_cast<bf16x8*>(orow + c * 8) = v;
        }
    }
}

// ---------------------------------------------------------------------------
// Orchestration. Two paths:
//  FAST (ws_size >= 112 MB): all scratch in ws, d_out written once (fp32 out).
//    ws: Qb[0:32M] Kb[32:40M] Vb[40:48M] xb[48:80M] Wt[80:112M]
//        Vt[48:56M] overlays xb after xb is dead (post V-GEMM).
//  FALLBACK (else): round-2 proven path (fp32-input gemm_to).
// ---------------------------------------------------------------------------
extern "C" void kernel_launch(void* const* d_in, const int* in_sizes, int n_in,
                              void* d_out, int out_size, void* d_ws, size_t ws_size,
                              hipStream_t stream)
{
    const float* x  = (const float*)d_in[0];
    const float* Wq = (const float*)d_in[1];
    const float* Wk = (const float*)d_in[2];
    const float* Wv = (const float*)d_in[3];
    const float* Wo = (const float*)d_in[4];
    float* out = (float*)d_out;

    char* ws = (char*)d_ws;
    dim3 blk(256);
    dim3 ablk(64);

    if (ws_size >= 112 * MBYTE) {
        // ---------------- FAST PATH: scratch entirely in workspace ----------
        __hip_bfloat16* Qb = (__hip_bfloat16*)(ws +  0 * MBYTE);
        __hip_bfloat16* Kb = (__hip_bfloat16*)(ws + 32 * MBYTE);
        __hip_bfloat16* Vb = (__hip_bfloat16*)(ws + 40 * MBYTE);
        __hip_bfloat16* xb = (__hip_bfloat16*)(ws + 48 * MBYTE);
        __hip_bfloat16* Vt = (__hip_bfloat16*)(ws + 48 * MBYTE);   // overlays dead xb
        __hip_bfloat16* Wt = (__hip_bfloat16*)(ws + 80 * MBYTE);

        cast_f2b<<<(NTOK * HIDDEN / 8 + 255) / 256, blk, 0, stream>>>(
            x, xb, (size_t)NTOK * HIDDEN / 8);

        // Q = xb @ Wq
        transpose_cast<<<dim3(HIDDEN / 32, HIDDEN / 32), blk, 0, stream>>>(Wq, HIDDEN, Wt, HIDDEN);
        gemm128r<__hip_bfloat16><<<dim3(HIDDEN / GBN, NTOK / GBM), blk, 0, stream>>>(
            xb, Wt, Qb, NTOK, HIDDEN, HIDDEN, HIDDEN);

        // K = xb @ Wk
        transpose_cast<<<dim3(HIDDEN / 32, KVDIM / 32), blk, 0, stream>>>(Wk, KVDIM, Wt, HIDDEN);
        gemm128r<__hip_bfloat16><<<dim3(KVDIM / GBN, NTOK / GBM), blk, 0, stream>>>(
            xb, Wt, Kb, NTOK, KVDIM, HIDDEN, KVDIM);

        // V = xb @ Wv  (last consumer of xb)
        transpose_cast<<<dim3(HIDDEN / 32, KVDIM / 32), blk, 0, stream>>>(Wv, KVDIM, Wt, HIDDEN);
        gemm128r<__hip_bfloat16><<<dim3(KVDIM / GBN, NTOK / GBM), blk, 0, stream>>>(
            xb, Wt, Vb, NTOK, KVDIM, HIDDEN, KVDIM);

        // RoPE in place
        {
            size_t totq = (size_t)NTOK * NHQ * 64;
            size_t totk = (size_t)NTOK * NHKV * 64;
            rope_kernel<<<(unsigned)((totq + 255) / 256), blk, 0, stream>>>(Qb, NHQ,  totq);
            rope_kernel<<<(unsigned)((totk + 255) / 256), blk, 0, stream>>>(Kb, NHKV, totk);
        }

        // V^T over dead xb region
        transpose_v<<<dim3(SEQ / 32, KVDIM / 32, BATCH), blk, 0, stream>>>(Vb, Vt);

        // wave-per-block: BATCH*NHKV*(SEQ/32)*4 = 4096 blocks of 64 threads
        attn_mfma<<<BATCH * NHKV * (SEQ / 32) * 4, ablk, 0, stream>>>(Qb, Kb, Vt, Qb);

        // out = O @ Wo (full Wo^T fits in Wt region)
        transpose_cast<<<dim3(HIDDEN / 32, HIDDEN / 32), blk, 0, stream>>>(Wo, HIDDEN, Wt, HIDDEN);
        gemm128r<float><<<dim3(HIDDEN / GBN, NTOK / GBM), blk, 0, stream>>>(
            Qb, Wt, out, NTOK, HIDDEN, HIDDEN, HIDDEN);
    } else {
        // ---------------- FALLBACK: round-2 proven path ---------------------
        __hip_bfloat16* Qb = (__hip_bfloat16*)ws;
        __hip_bfloat16* Kb = (__hip_bfloat16*)(ws + (size_t)NTOK * HIDDEN * 2);
        __hip_bfloat16* Vb = (__hip_bfloat16*)(ws + (size_t)NTOK * HIDDEN * 2
                                                  + (size_t)NTOK * KVDIM * 2);

        const size_t base_ws  = (size_t)NTOK * HIDDEN * 2 + 2 * (size_t)NTOK * KVDIM * 2;
        const size_t vt_bytes = (size_t)NTOK * KVDIM * 2;
        __hip_bfloat16* Vtr = (ws_size >= base_ws + vt_bytes)
                            ? (__hip_bfloat16*)(ws + base_ws)
                            : (__hip_bfloat16*)d_out;

        gemm_to<float, float, __hip_bfloat16><<<dim3(HIDDEN / BN, NTOK / BM), blk, 0, stream>>>(
            x, Wq, Qb, NTOK, HIDDEN, HIDDEN);
        gemm_to<float, float, __hip_bfloat16><<<dim3(KVDIM / BN, NTOK / BM), blk, 0, stream>>>(
            x, Wk, Kb, NTOK, KVDIM, HIDDEN);
        gemm_to<float, float, __hip_bfloat16><<<dim3(KVDIM / BN, NTOK / BM), blk, 0, stream>>>(
            x, Wv, Vb, NTOK, KVDIM, HIDDEN);

        {
            size_t totq = (size_t)NTOK * NHQ * 64;
            size_t totk = (size_t)NTOK * NHKV * 64;
            rope_kernel<<<(unsigned)((totq + 255) / 256), blk, 0, stream>>>(Qb, NHQ,  totq);
            rope_kernel<<<(unsigned)((totk + 255) / 256), blk, 0, stream>>>(Kb, NHKV, totk);
        }

        transpose_v<<<dim3(SEQ / 32, KVDIM / 32, BATCH), blk, 0, stream>>>(Vb, Vtr);

        attn_mfma<<<BATCH * NHKV * (SEQ / 32) * 4, ablk, 0, stream>>>(Qb, Kb, Vtr, Qb);

        gemm_to<__hip_bfloat16, float, float><<<dim3(HIDDEN / BN, NTOK / BM), blk, 0, stream>>>(
            Qb, Wo, out, NTOK, HIDDEN, HIDDEN);
    }
}